// Round 5
// baseline (123.927 us; speedup 1.0000x reference)
//
#include <hip/hip_runtime.h>
#include <cfloat>

typedef unsigned long long u64;

#define CDESC 32
#define N0 4096
#define N1 512

// sign-transformed float bits: monotone u32 over the float total order
__device__ __forceinline__ unsigned fbits_mono(float d) {
    unsigned b = __float_as_uint(d);
    return (d >= 0.f) ? (b | 0x80000000u) : ~b;
}

__device__ __forceinline__ void wave_reduce_atomic(float v, float* acc) {
#pragma unroll
    for (int off = 32; off > 0; off >>= 1) v += __shfl_down(v, off, 64);
    if ((threadIdx.x & 63) == 0) atomicAdd(acc, v);
}

// broadcast lane L's float to all lanes via v_readlane (VALU pipe, no DS/SMEM)
__device__ __forceinline__ float bcast(float v, int L) {
    return __int_as_float(__builtin_amdgcn_readlane(__float_as_int(v), L));
}

// ======================= K1: fused x+y filter (both stages) + transpose =======================
// R11 (verified): y-filter fused in-plane. blocks 0..767 (x2 sides): one
// (channel, z) input plane staged to LDS; x-filter to xf16/xf8 (LDS, padded
// strides 17/9); per-plane y-filter -> only [16][16] and [8][8] to HBM.
// Separable per-axis normalization == jax.image.resize.
// blocks 768..1055: descriptor transpose [b][32][N] -> [b][N][32] (verified R7).
__global__ __launch_bounds__(256) void pass1_fused(
        const float* __restrict__ csrc, const float* __restrict__ ctgt,
        const float* __restrict__ sd0, const float* __restrict__ td0,
        const float* __restrict__ sd1, const float* __restrict__ td1,
        float* __restrict__ x16a, float* __restrict__ x16b,
        float* __restrict__ x8a,  float* __restrict__ x8b,
        float* __restrict__ sd0T, float* __restrict__ td0T,
        float* __restrict__ sd1T, float* __restrict__ td1T,
        float* __restrict__ acc) {
    __shared__ __align__(16) float sRow[65 * 64];  // padded 64x64 plane (16.25 KB)
    __shared__ float xf16[64 * 17];                // x-filtered [y64][x16], pad 17
    __shared__ float xf8[64 * 9];                  // x-filtered [y64][x8],  pad 9
    const int tid = threadIdx.x;
    const int bx  = blockIdx.x, by = blockIdx.y;
    if (by == 0 && bx == 0 && tid < 4) acc[tid] = 0.f;

    if (bx < 768) {
        int bc = bx >> 6, z = bx & 63;             // channel-plane, z-slice
        const float* in = by ? ctgt : csrc;
        float* o16 = by ? x16b : x16a;
        float* o8  = by ? x8b  : x8a;
        const float4* src = (const float4*)(in + (size_t)(bc * 64 + z) * 4096);
#pragma unroll
        for (int k = 0; k < 4; ++k) {              // coalesced 16 KB stage, padded rows
            float4 v = src[tid + k * 256];
            int g = tid + k * 256;                 // float4 index 0..1023
            int y = g >> 4, j = (g & 15) * 4;      // row, col (j%4==0, no pad crossing)
            float* p = &sRow[y * 65 + j];          // scalar writes: 2-way banks (free)
            p[0] = v.x; p[1] = v.y; p[2] = v.z; p[3] = v.w;
        }
        __syncthreads();
#pragma unroll
        for (int k = 0; k < 6; ++k) {              // x-filter: 1536 vals, 6/thread
            int o = tid + k * 256;
            if (o < 1024) {                        // S=16, R=4 (k=0..3: no divergence)
                int y = o >> 4, xo = o & 15;
                int j0 = 4 * xo - 2;
                float sum = 0.f, wsum = 0.f;
#pragma unroll
                for (int t = 0; t < 8; ++t) {
                    int j = j0 + t;
                    float w = 1.f - fabsf((float)t - 3.5f) / 4.f;
                    if (j >= 0 && j < 64) { sum = fmaf(w, sRow[y * 65 + j], sum); wsum += w; }
                }
                xf16[y * 17 + xo] = sum / wsum;
            } else {                               // S=8, R=8 (k=4,5)
                int o2 = o - 1024;
                int y = o2 >> 3, xo = o2 & 7;
                int j0 = 8 * xo - 4;
                float sum = 0.f, wsum = 0.f;
#pragma unroll
                for (int t = 0; t < 16; ++t) {
                    int j = j0 + t;
                    float w = 1.f - fabsf((float)t - 7.5f) / 8.f;
                    if (j >= 0 && j < 64) { sum = fmaf(w, sRow[y * 65 + j], sum); wsum += w; }
                }
                xf8[y * 9 + xo] = sum / wsum;
            }
        }
        __syncthreads();
        {                                          // y-filter S=16: 256 outs, 1/thread
            int y2 = tid >> 4, x = tid & 15;
            int j0 = 4 * y2 - 2;
            float sum = 0.f, wsum = 0.f;
#pragma unroll
            for (int t = 0; t < 8; ++t) {
                int j = j0 + t;
                float w = 1.f - fabsf((float)t - 3.5f) / 4.f;
                if (j >= 0 && j < 64) { sum = fmaf(w, xf16[j * 17 + x], sum); wsum += w; }
            }
            o16[bc * 16384 + z * 256 + y2 * 16 + x] = sum / wsum;  // coalesced 1 KB
        }
        if (tid < 64) {                            // y-filter S=8: 64 outs
            int y2 = tid >> 3, x = tid & 7;
            int j0 = 8 * y2 - 4;
            float sum = 0.f, wsum = 0.f;
#pragma unroll
            for (int t = 0; t < 16; ++t) {
                int j = j0 + t;
                float w = 1.f - fabsf((float)t - 7.5f) / 8.f;
                if (j >= 0 && j < 64) { sum = fmaf(w, xf8[j * 9 + x], sum); wsum += w; }
            }
            o8[bc * 4096 + z * 64 + y2 * 8 + x] = sum / wsum;      // coalesced 256 B
        }
    } else {
        // ---- transpose [b][32][N] -> [b][N][32], 64-point tiles (verified R7) ----
        __shared__ float tile[64 * 33];
        int tl = bx - 768;                         // 0..287
        const float* din; float* dout; int N, b, n0;
        if (tl < 256) { din = by ? td0 : sd0; dout = by ? td0T : sd0T;
                        N = N0; b = tl >> 6; n0 = (tl & 63) * 64; }
        else { tl -= 256; din = by ? td1 : sd1; dout = by ? td1T : sd1T;
               N = N1; b = tl >> 3; n0 = (tl & 7) * 64; }
#pragma unroll
        for (int i = 0; i < 8; ++i) {              // load: coalesced 64-float rows
            int idx = tid + i * 256;
            int c = idx >> 6, j = idx & 63;
            tile[j * 33 + c] = din[((size_t)b * CDESC + c) * N + n0 + j];
        }
        __syncthreads();
#pragma unroll
        for (int i = 0; i < 8; ++i) {              // store: contiguous 32-float points
            int idx = tid + i * 256;
            int p = idx >> 5, c = idx & 31;
            dout[((size_t)b * N + n0 + p) * CDESC + c] = tile[p * 33 + c];
        }
    }
}

// ======================= K2: z-filter only (both stages) =======================
// R11 (verified): pure 8-tap (S=16) / 16-tap (S=8) z-filter, coalesced 256 B
// reads per tap. Target side written PRE-TRANSFORMED (-2x,-2y,-2z,|t|^2).
__global__ __launch_bounds__(256) void pass2z(
        const float* __restrict__ x16a, const float* __restrict__ x16b,
        const float* __restrict__ x8a,  const float* __restrict__ x8b,
        float4* __restrict__ ps0, float4* __restrict__ pt0,
        float4* __restrict__ ps1, float4* __restrict__ pt1) {
    int gid = blockIdx.x * 256 + threadIdx.x;
    if (blockIdx.x < 128) {                        // stage-0: 32768 points
        int side = gid >> 14, r = gid & 16383;
        int b = r >> 12, n = r & 4095;
        int x = n & 15, y = (n >> 4) & 15, z = n >> 8;
        const float* t = side ? x16b : x16a;
        const float* base = t + (size_t)b * 49152 + y * 16 + x;  // b*3ch*16384
        float a0 = 0.f, a1 = 0.f, a2 = 0.f, wzs = 0.f;
#pragma unroll
        for (int tt = 0; tt < 8; ++tt) {
            float w = 1.f - fabsf((float)tt - 3.5f) * 0.25f;
            int jz = 4 * z - 2 + tt;
            if ((unsigned)jz < 64u) {
                const float* p = base + jz * 256;
                a0 = fmaf(w, p[0],     a0);
                a1 = fmaf(w, p[16384], a1);
                a2 = fmaf(w, p[32768], a2);
                wzs += w;
            }
        }
        float inv = 1.f / wzs;
        a0 *= inv; a1 *= inv; a2 *= inv;
        float sq = a0 * a0 + a1 * a1 + a2 * a2;
        if (side) pt0[b * N0 + n] = make_float4(-2.f * a0, -2.f * a1, -2.f * a2, sq);
        else      ps0[b * N0 + n] = make_float4(a0, a1, a2, sq);
    } else {                                       // stage-1: 4096 points
        int g = gid - 32768;
        int side = g >> 11, r = g & 2047;
        int b = r >> 9, n = r & 511;
        int x = n & 7, y = (n >> 3) & 7, z = n >> 6;
        const float* t = side ? x8b : x8a;
        const float* base = t + (size_t)b * 12288 + y * 8 + x;   // b*3ch*4096
        float a0 = 0.f, a1 = 0.f, a2 = 0.f, wzs = 0.f;
#pragma unroll
        for (int tt = 0; tt < 16; ++tt) {
            float w = 1.f - fabsf((float)tt - 7.5f) * 0.125f;
            int jz = 8 * z - 4 + tt;
            if ((unsigned)jz < 64u) {
                const float* p = base + jz * 64;
                a0 = fmaf(w, p[0],    a0);
                a1 = fmaf(w, p[4096], a1);
                a2 = fmaf(w, p[8192], a2);
                wzs += w;
            }
        }
        float inv = 1.f / wzs;
        a0 *= inv; a1 *= inv; a2 *= inv;
        float sq = a0 * a0 + a1 * a1 + a2 * a2;
        if (side) pt1[b * N1 + n] = make_float4(-2.f * a0, -2.f * a1, -2.f * a2, sq);
        else      ps1[b * N1 + n] = make_float4(a0, a1, a2, sq);
    }
}

// cosine of two point-major 32-float descriptors (coalesced float4 reads)
__device__ __forceinline__ float cos_pm(const float* __restrict__ sT,
                                        const float* __restrict__ tT,
                                        size_t si, size_t ti) {
    const float4* s = (const float4*)(sT + si * CDESC);
    const float4* t = (const float4*)(tT + ti * CDESC);
    float num = 0.f, s2 = 0.f, t2 = 0.f;
#pragma unroll
    for (int c = 0; c < 8; ++c) {
        float4 a = s[c], g = t[c];
        num = fmaf(a.x, g.x, fmaf(a.y, g.y, fmaf(a.z, g.z, fmaf(a.w, g.w, num))));
        s2  = fmaf(a.x, a.x, fmaf(a.y, a.y, fmaf(a.z, a.z, fmaf(a.w, a.w, s2))));
        t2  = fmaf(g.x, g.x, fmaf(g.y, g.y, fmaf(g.z, g.z, fmaf(g.w, g.w, t2))));
    }
    return num / (fmaxf(sqrtf(s2), 1e-8f) * fmaxf(sqrtf(t2), 1e-8f));
}

// d2 (minus the constant |s|^2 term) from a point P and a pre-transformed candidate Q
__device__ __forceinline__ float dist_pm(float4 P, float4 Q) {
    return fmaf(P.x, Q.x, fmaf(P.y, Q.y, fmaf(P.z, Q.z, Q.w)));
}

// 16-candidate distance batch via readlane broadcast of lane-resident Q4.
// Lane L holds candidate (k0base + L); broadcasting lane g*16+u gives candidate
// (k0base + g*16 + u) to all lanes -- same values, same fmaf chain as the LDS
// version -> bit-exact. All lanes active (no divergence in the scan loop).
#define DIST16(darr, Qv, G)                                                    \
    _Pragma("unroll")                                                          \
    for (int u = 0; u < 16; ++u) {                                             \
        float qx = bcast((Qv).x, (G) * 16 + u);                                \
        float qy = bcast((Qv).y, (G) * 16 + u);                                \
        float qz = bcast((Qv).z, (G) * 16 + u);                                \
        float qw = bcast((Qv).w, (G) * 16 + u);                                \
        darr[u] = fmaf(P.x, qx, fmaf(P.y, qy, fmaf(P.z, qz, qw)));             \
    }

#define MINTREE16(darr, bm)                                                    \
    float e0 = fminf(darr[0],  darr[1]),  e1 = fminf(darr[2],  darr[3]);       \
    float e2 = fminf(darr[4],  darr[5]),  e3 = fminf(darr[6],  darr[7]);       \
    float e4 = fminf(darr[8],  darr[9]),  e5 = fminf(darr[10], darr[11]);      \
    float e6 = fminf(darr[12], darr[13]), e7 = fminf(darr[14], darr[15]);      \
    float f0 = fminf(e0, e1), f1 = fminf(e2, e3);                              \
    float f2 = fminf(e4, e5), f3 = fminf(e6, e7);                              \
    float bm = fminf(fminf(f0, f1), fminf(f2, f3));

// ======================= K3: argmin + cosine =======================
// R12: candidate broadcast via VALU (v_readlane), not DS. The old loop issued
// 1024 ds_read_b128/wave on the CU-shared DS pipe (~25-49K cyc/CU serialized);
// now each wave loads 64 candidates coalesced into lanes (1 global_load_dwordx4
// from the L1-resident 16 KB window) and broadcasts with imm-lane readlanes:
// ~9 VALU/candidate on the per-SIMD VALU pipe (4x wider than DS). 64 KB LDS
// staging deleted (2 KB keys only) -> no occupancy cap, tail co-schedules.
// Batch order, strict-< compare, descending first-match re-scan (per-lane
// global gather, same memory) identical -> bit-exact vs R3.
__global__ __launch_bounds__(256) void nn_cos_all(
        const float4* __restrict__ ps0, const float4* __restrict__ pt0,
        const float* __restrict__ sd0T, const float* __restrict__ td0T,
        const float4* __restrict__ ps1, const float4* __restrict__ pt1,
        const float* __restrict__ sd1T, const float* __restrict__ td1T,
        float* acc, float* __restrict__ out) {
    __shared__ u64 keys[256];
    const int tid = threadIdx.x;
    const int bx  = blockIdx.x;
    const int lane = tid & 63;

    if (bx < 256) {
        int b = bx >> 6, ptile = bx & 63;
        int w = tid >> 6;
        int n = ptile * 64 + lane;
        float4 P = ps0[b * N0 + n];
        const float4* tp = pt0 + b * N0 + w * 1024;        // wave's m-window
        float best = FLT_MAX; int bbase = 0;
        for (int k0 = 0; k0 < 1024; k0 += 64) {
            float4 Q4 = tp[k0 + lane];                     // 64 cands -> lanes (1 KB coalesced)
#pragma unroll
            for (int g = 0; g < 4; ++g) {                  // four 16-batches, ascending
                float d[16];
                DIST16(d, Q4, g)
                MINTREE16(d, bm)
                if (bm < best) { best = bm; bbase = k0 + g * 16; }  // strict <
            }
        }
        int bi = 0;
        {
            const float4* tpr = tp + bbase;                // per-lane winning batch
#pragma unroll
            for (int u = 15; u >= 0; --u) {                // descending: ends at FIRST match
                float dv = dist_pm(P, tpr[u]);             // per-lane gather, same memory
                if (dv == best) bi = u;
            }
        }
        u64 key = ((u64)fbits_mono(best) << 32) | (unsigned)(w * 1024 + bbase + bi);
        keys[w * 64 + lane] = key;
        __syncthreads();
        if (tid < 64) {
            u64 k0 = keys[tid],       k1 = keys[tid + 64];
            u64 k2 = keys[tid + 128], k3 = keys[tid + 192];
            u64 ka = k0 < k1 ? k0 : k1;
            u64 kb = k2 < k3 ? k2 : k3;
            u64 kk = ka < kb ? ka : kb;                    // windows ascending + u64 min
            int nearest = (int)(unsigned)(kk & 0xFFFFFFFFull);
            int n2 = ptile * 64 + tid;
            float cosv = cos_pm(sd0T, td0T, (size_t)b * N0 + n2,
                                (size_t)b * N0 + nearest);
            wave_reduce_atomic(cosv, acc + 0);
        }
    } else {
        int bb = bx - 256;
        int b = bb >> 1;
        int n = (bb & 1) * 256 + tid;
        float4 P = ps1[b * N1 + n];
        const float4* tp = pt1 + b * N1;
        float best = FLT_MAX; int bbase = 0;
        for (int k0 = 0; k0 < N1; k0 += 64) {
            float4 Q4 = tp[k0 + lane];
#pragma unroll
            for (int g = 0; g < 4; ++g) {
                float d[16];
                DIST16(d, Q4, g)
                MINTREE16(d, bm)
                if (bm < best) { best = bm; bbase = k0 + g * 16; }
            }
        }
        int bi = 0;
        {
            const float4* tpr = tp + bbase;
#pragma unroll
            for (int u = 15; u >= 0; --u) {
                float dv = dist_pm(P, tpr[u]);
                if (dv == best) bi = u;
            }
        }
        float cosv = cos_pm(sd1T, td1T, (size_t)b * N1 + n,
                            (size_t)b * N1 + bbase + bi);
        wave_reduce_atomic(cosv, acc + 1);
    }

    __syncthreads();                               // block's atomics all issued
    if (tid == 0) {
        __threadfence();
        unsigned old = atomicAdd((unsigned*)(acc + 2), 1u);
        if (old == 263u) {                         // last of 264 blocks
            float a0 = atomicAdd(acc + 0, 0.f);
            float a1 = atomicAdd(acc + 1, 0.f);
            out[0] = 1.f - 0.5f * (a0 * (1.f / 16384.f) + a1 * (1.f / 2048.f));
        }
    }
}

extern "C" void kernel_launch(void* const* d_in, const int* in_sizes, int n_in,
                              void* d_out, int out_size, void* d_ws, size_t ws_size,
                              hipStream_t stream) {
    const float* c_src = (const float*)d_in[0];   // [4,3,64,64,64]
    const float* c_tgt = (const float*)d_in[1];
    const float* sd0   = (const float*)d_in[2];   // [4,32,16,16,16]
    const float* td0   = (const float*)d_in[3];
    const float* sd1   = (const float*)d_in[4];   // [4,32,8,8,8]
    const float* td1   = (const float*)d_in[5];
    float* out = (float*)d_out;

    char* ws = (char*)d_ws;
    float* acc  = (float*)ws;                      // [0]=sum0 [1]=sum1 [2]=ticket
    float* x16a = (float*)(ws + 256);              // 196608 floats each [bc][z][16][16]
    float* x16b = x16a + 196608;
    float* x8a  = x16b + 196608;                   // 49152 floats each [bc][z][8][8]
    float* x8b  = x8a + 49152;
    float4* ps0 = (float4*)(x8b + 49152);          // 16384 float4
    float4* pt0 = ps0 + 16384;
    float4* ps1 = pt0 + 16384;                     // 2048 float4
    float4* pt1 = ps1 + 2048;
    float* sd0T = (float*)(pt1 + 2048);            // 524288 floats each
    float* td0T = sd0T + 524288;
    float* sd1T = td0T + 524288;                   // 65536 floats each
    float* td1T = sd1T + 65536;

    pass1_fused<<<dim3(1056, 2), 256, 0, stream>>>(c_src, c_tgt, sd0, td0, sd1, td1,
                                                   x16a, x16b, x8a, x8b,
                                                   sd0T, td0T, sd1T, td1T, acc);
    pass2z<<<144, 256, 0, stream>>>(x16a, x16b, x8a, x8b, ps0, pt0, ps1, pt1);
    nn_cos_all<<<264, 256, 0, stream>>>(ps0, pt0, sd0T, td0T, ps1, pt1,
                                        sd1T, td1T, acc, out);
}

// Round 6
// 115.659 us; speedup vs baseline: 1.0715x; 1.0715x over previous
//
#include <hip/hip_runtime.h>
#include <cfloat>

typedef unsigned long long u64;

#define CDESC 32
#define N0 4096
#define N1 512

// sign-transformed float bits: monotone u32 over the float total order
__device__ __forceinline__ unsigned fbits_mono(float d) {
    unsigned b = __float_as_uint(d);
    return (d >= 0.f) ? (b | 0x80000000u) : ~b;
}

__device__ __forceinline__ void wave_reduce_atomic(float v, float* acc) {
#pragma unroll
    for (int off = 32; off > 0; off >>= 1) v += __shfl_down(v, off, 64);
    if ((threadIdx.x & 63) == 0) atomicAdd(acc, v);
}

// ======================= K1: fused x+y filter (both stages) + transpose =======================
// R13: branch-free taps. sRow zero-padded to cols [-4,67] (stride 73, odd ->
// all tap reads <=2-way banked = free); xf16/xf8 zero-padded rows (strides
// 19/9, <=2-way). wsum from 2-entry LUT: edge sums (3.5/7.0) are exact fp sums
// of the same weights -> identical division bits; zero-pad taps add exactly 0.
// Tap body = ds_read + fma only. LDS 31->26 KB (6 blocks/CU).
// blocks 0..767 (x2 sides): per-(channel,z)-plane x-filter then y-filter; only
// [16][16] and [8][8] outputs to HBM (verified R11 structure).
// blocks 768..1055: descriptor transpose [b][32][N] -> [b][N][32] (verified R7).
__global__ __launch_bounds__(256) void pass1_fused(
        const float* __restrict__ csrc, const float* __restrict__ ctgt,
        const float* __restrict__ sd0, const float* __restrict__ td0,
        const float* __restrict__ sd1, const float* __restrict__ td1,
        float* __restrict__ x16a, float* __restrict__ x16b,
        float* __restrict__ x8a,  float* __restrict__ x8b,
        float* __restrict__ sd0T, float* __restrict__ td0T,
        float* __restrict__ sd1T, float* __restrict__ td1T,
        float* __restrict__ acc) {
    __shared__ __align__(16) float lds[6612];
    float* sRowP = lds;            // [64][73], col 4+j for j in [-4,67]
    float* xf16P = lds + 4672;     // [68][19], row 2+j for j in [-2,65]
    float* xf8P  = lds + 5964;     // [72][9],  row 4+j for j in [-4,67]
    const int tid = threadIdx.x;
    const int bx  = blockIdx.x, by = blockIdx.y;
    if (by == 0 && bx == 0 && tid < 4) acc[tid] = 0.f;

    if (bx < 768) {
        int bc = bx >> 6, z = bx & 63;             // channel-plane, z-slice
        const float* in = by ? ctgt : csrc;
        float* o16 = by ? x16b : x16a;
        float* o8  = by ? x8b  : x8a;
        // ---- zero pads (parallel with staging, before first sync) ----
        if (tid < 512) {                           // sRowP: 8 pad cols x 64 rows
            int r = tid >> 3, c = tid & 7;
            sRowP[r * 73 + (c < 4 ? c : 64 + c)] = 0.f;
        }
        if (tid < 76) {                            // xf16P: rows 0,1,66,67
            int r = tid / 19, c = tid % 19;
            xf16P[(r < 2 ? r : r + 62) * 19 + c] = 0.f;
        }
        if (tid < 72) {                            // xf8P: rows 0..3, 68..71
            int r = tid / 9, c = tid % 9;
            xf8P[(r < 4 ? r : r + 60) * 9 + c] = 0.f;
        }
        const float4* src = (const float4*)(in + (size_t)(bc * 64 + z) * 4096);
#pragma unroll
        for (int k = 0; k < 4; ++k) {              // coalesced 16 KB stage, padded rows
            float4 v = src[tid + k * 256];
            int g = tid + k * 256;                 // float4 index 0..1023
            int y = g >> 4, j = (g & 15) * 4;      // row, col (scalar: 2-way banks)
            float* p = &sRowP[y * 73 + 4 + j];
            p[0] = v.x; p[1] = v.y; p[2] = v.z; p[3] = v.w;
        }
        __syncthreads();
#pragma unroll
        for (int k = 0; k < 6; ++k) {              // x-filter: 1536 vals, 6/thread
            int o = tid + k * 256;
            if (o < 1024) {                        // S=16, R=4 (k=0..3: no divergence)
                int y = o >> 4, xo = o & 15;
                const float* r = &sRowP[y * 73 + 4 * xo + 2];  // j0=4xo-2 -> col 4xo+2
                float sum = 0.f;
#pragma unroll
                for (int t = 0; t < 8; ++t) {
                    float w = 1.f - fabsf((float)t - 3.5f) * 0.25f;
                    sum = fmaf(w, r[t], sum);      // pads contribute exactly 0
                }
                float wsum = (xo == 0 || xo == 15) ? 3.5f : 4.0f;
                xf16P[(y + 2) * 19 + xo] = sum / wsum;
            } else {                               // S=8, R=8 (k=4,5)
                int o2 = o - 1024;
                int y = o2 >> 3, xo = o2 & 7;
                const float* r = &sRowP[y * 73 + 8 * xo];      // j0=8xo-4 -> col 8xo
                float sum = 0.f;
#pragma unroll
                for (int t = 0; t < 16; ++t) {
                    float w = 1.f - fabsf((float)t - 7.5f) * 0.125f;
                    sum = fmaf(w, r[t], sum);
                }
                float wsum = (xo == 0 || xo == 7) ? 7.f : 8.f;
                xf8P[(y + 4) * 9 + xo] = sum / wsum;
            }
        }
        __syncthreads();
        {                                          // y-filter S=16: 256 outs, 1/thread
            int y2 = tid >> 4, x = tid & 15;
            float sum = 0.f;
#pragma unroll
            for (int t = 0; t < 8; ++t) {          // rows 4y2-2+t -> padded 4y2+t
                float w = 1.f - fabsf((float)t - 3.5f) * 0.25f;
                sum = fmaf(w, xf16P[(4 * y2 + t) * 19 + x], sum);
            }
            float wsum = (y2 == 0 || y2 == 15) ? 3.5f : 4.0f;
            o16[bc * 16384 + z * 256 + y2 * 16 + x] = sum / wsum;  // coalesced 1 KB
        }
        if (tid < 64) {                            // y-filter S=8: 64 outs
            int y2 = tid >> 3, x = tid & 7;
            float sum = 0.f;
#pragma unroll
            for (int t = 0; t < 16; ++t) {         // rows 8y2-4+t -> padded 8y2+t
                float w = 1.f - fabsf((float)t - 7.5f) * 0.125f;
                sum = fmaf(w, xf8P[(8 * y2 + t) * 9 + x], sum);
            }
            float wsum = (y2 == 0 || y2 == 7) ? 7.f : 8.f;
            o8[bc * 4096 + z * 64 + y2 * 8 + x] = sum / wsum;      // coalesced 256 B
        }
    } else {
        // ---- transpose [b][32][N] -> [b][N][32], 64-point tiles (verified R7) ----
        float* tile = lds;                         // 64*33 = 2112 floats, fits overlay
        int tl = bx - 768;                         // 0..287
        const float* din; float* dout; int N, b, n0;
        if (tl < 256) { din = by ? td0 : sd0; dout = by ? td0T : sd0T;
                        N = N0; b = tl >> 6; n0 = (tl & 63) * 64; }
        else { tl -= 256; din = by ? td1 : sd1; dout = by ? td1T : sd1T;
               N = N1; b = tl >> 3; n0 = (tl & 7) * 64; }
#pragma unroll
        for (int i = 0; i < 8; ++i) {              // load: coalesced 64-float rows
            int idx = tid + i * 256;
            int c = idx >> 6, j = idx & 63;
            tile[j * 33 + c] = din[((size_t)b * CDESC + c) * N + n0 + j];
        }
        __syncthreads();
#pragma unroll
        for (int i = 0; i < 8; ++i) {              // store: contiguous 32-float points
            int idx = tid + i * 256;
            int p = idx >> 5, c = idx & 31;
            dout[((size_t)b * N + n0 + p) * CDESC + c] = tile[p * 33 + c];
        }
    }
}

// ======================= K2: z-filter only (both stages) =======================
// R11 (verified): pure 8-tap (S=16) / 16-tap (S=8) z-filter, coalesced 256 B
// reads per tap. Target side written PRE-TRANSFORMED (-2x,-2y,-2z,|t|^2).
__global__ __launch_bounds__(256) void pass2z(
        const float* __restrict__ x16a, const float* __restrict__ x16b,
        const float* __restrict__ x8a,  const float* __restrict__ x8b,
        float4* __restrict__ ps0, float4* __restrict__ pt0,
        float4* __restrict__ ps1, float4* __restrict__ pt1) {
    int gid = blockIdx.x * 256 + threadIdx.x;
    if (blockIdx.x < 128) {                        // stage-0: 32768 points
        int side = gid >> 14, r = gid & 16383;
        int b = r >> 12, n = r & 4095;
        int x = n & 15, y = (n >> 4) & 15, z = n >> 8;
        const float* t = side ? x16b : x16a;
        const float* base = t + (size_t)b * 49152 + y * 16 + x;  // b*3ch*16384
        float a0 = 0.f, a1 = 0.f, a2 = 0.f, wzs = 0.f;
#pragma unroll
        for (int tt = 0; tt < 8; ++tt) {
            float w = 1.f - fabsf((float)tt - 3.5f) * 0.25f;
            int jz = 4 * z - 2 + tt;
            if ((unsigned)jz < 64u) {
                const float* p = base + jz * 256;
                a0 = fmaf(w, p[0],     a0);
                a1 = fmaf(w, p[16384], a1);
                a2 = fmaf(w, p[32768], a2);
                wzs += w;
            }
        }
        float inv = 1.f / wzs;
        a0 *= inv; a1 *= inv; a2 *= inv;
        float sq = a0 * a0 + a1 * a1 + a2 * a2;
        if (side) pt0[b * N0 + n] = make_float4(-2.f * a0, -2.f * a1, -2.f * a2, sq);
        else      ps0[b * N0 + n] = make_float4(a0, a1, a2, sq);
    } else {                                       // stage-1: 4096 points
        int g = gid - 32768;
        int side = g >> 11, r = g & 2047;
        int b = r >> 9, n = r & 511;
        int x = n & 7, y = (n >> 3) & 7, z = n >> 6;
        const float* t = side ? x8b : x8a;
        const float* base = t + (size_t)b * 12288 + y * 8 + x;   // b*3ch*4096
        float a0 = 0.f, a1 = 0.f, a2 = 0.f, wzs = 0.f;
#pragma unroll
        for (int tt = 0; tt < 16; ++tt) {
            float w = 1.f - fabsf((float)tt - 7.5f) * 0.125f;
            int jz = 8 * z - 4 + tt;
            if ((unsigned)jz < 64u) {
                const float* p = base + jz * 64;
                a0 = fmaf(w, p[0],    a0);
                a1 = fmaf(w, p[4096], a1);
                a2 = fmaf(w, p[8192], a2);
                wzs += w;
            }
        }
        float inv = 1.f / wzs;
        a0 *= inv; a1 *= inv; a2 *= inv;
        float sq = a0 * a0 + a1 * a1 + a2 * a2;
        if (side) pt1[b * N1 + n] = make_float4(-2.f * a0, -2.f * a1, -2.f * a2, sq);
        else      ps1[b * N1 + n] = make_float4(a0, a1, a2, sq);
    }
}

// cosine of two point-major 32-float descriptors (coalesced float4 reads)
__device__ __forceinline__ float cos_pm(const float* __restrict__ sT,
                                        const float* __restrict__ tT,
                                        size_t si, size_t ti) {
    const float4* s = (const float4*)(sT + si * CDESC);
    const float4* t = (const float4*)(tT + ti * CDESC);
    float num = 0.f, s2 = 0.f, t2 = 0.f;
#pragma unroll
    for (int c = 0; c < 8; ++c) {
        float4 a = s[c], g = t[c];
        num = fmaf(a.x, g.x, fmaf(a.y, g.y, fmaf(a.z, g.z, fmaf(a.w, g.w, num))));
        s2  = fmaf(a.x, a.x, fmaf(a.y, a.y, fmaf(a.z, a.z, fmaf(a.w, a.w, s2))));
        t2  = fmaf(g.x, g.x, fmaf(g.y, g.y, fmaf(g.z, g.z, fmaf(g.w, g.w, t2))));
    }
    return num / (fmaxf(sqrtf(s2), 1e-8f) * fmaxf(sqrtf(t2), 1e-8f));
}

// d2 (minus the constant |s|^2 term) from a point P and a pre-transformed candidate Q
__device__ __forceinline__ float dist_pm(float4 P, float4 Q) {
    return fmaf(P.x, Q.x, fmaf(P.y, Q.y, fmaf(P.z, Q.z, Q.w)));
}

// ======================= K3: argmin + cosine (R3 measured-best body) =======================
// LDS-staged candidates (pure float4 copy; pre-transformed in pass2z), batch-16
// min-tree (chain-free) + strict-< batch compare + descending first-match re-scan
// == jnp.argmin first-min, bit-exact. 4 waves x 1024-candidate windows; combine
// via packed (mono(d)<<32|m) u64 keys in reused LDS. 264-ticket finalizer.
// (R10 SMEM and R12 readlane variants both measured SLOWER -- uniform-address
// ds_read_b128 broadcast is the fastest candidate path on this part.)
__global__ __launch_bounds__(256) void nn_cos_all(
        const float4* __restrict__ ps0, const float4* __restrict__ pt0,
        const float* __restrict__ sd0T, const float* __restrict__ td0T,
        const float4* __restrict__ ps1, const float4* __restrict__ pt1,
        const float* __restrict__ sd1T, const float* __restrict__ td1T,
        float* acc, float* __restrict__ out) {
    extern __shared__ __align__(16) char smraw[];  // 64 KB dynamic
    float4* sm = (float4*)smraw;
    const int tid = threadIdx.x;
    const int bx  = blockIdx.x;

    if (bx < 256) {
        int b = bx >> 6, ptile = bx & 63;
        const float4* tp = pt0 + b * N0;
        for (int i = tid; i < N0; i += 256)        // stage all 4096 targets (64 KB)
            sm[i] = tp[i];                         // pre-transformed in pass2z
        __syncthreads();
        int w = tid >> 6, lane = tid & 63;
        int n = ptile * 64 + lane;
        float4 P = ps0[b * N0 + n];
        const int m0 = w * 1024;                   // this wave's m-window
        float best = FLT_MAX; int bbase = 0;
        for (int k0 = 0; k0 < 1024; k0 += 16) {
            float d[16];
#pragma unroll
            for (int u = 0; u < 16; ++u)
                d[u] = dist_pm(P, sm[m0 + k0 + u]);  // broadcast, conflict-free
            float e0 = fminf(d[0],  d[1]),  e1 = fminf(d[2],  d[3]);
            float e2 = fminf(d[4],  d[5]),  e3 = fminf(d[6],  d[7]);
            float e4 = fminf(d[8],  d[9]),  e5 = fminf(d[10], d[11]);
            float e6 = fminf(d[12], d[13]), e7 = fminf(d[14], d[15]);
            float f0 = fminf(e0, e1), f1 = fminf(e2, e3);
            float f2 = fminf(e4, e5), f3 = fminf(e6, e7);
            float bm = fminf(fminf(f0, f1), fminf(f2, f3));
            if (bm < best) { best = bm; bbase = k0; }  // strict <: keeps first batch
        }
        int bi = 0;
#pragma unroll
        for (int u = 15; u >= 0; --u) {            // descending: ends at FIRST match
            float dv = dist_pm(P, sm[m0 + bbase + u]);
            if (dv == best) bi = u;
        }
        u64 key = ((u64)fbits_mono(best) << 32) | (unsigned)(m0 + bbase + bi);
        __syncthreads();                           // everyone done reading sm
        u64* keys = (u64*)smraw;                   // reuse LDS for combine
        keys[w * 64 + lane] = key;
        __syncthreads();
        if (tid < 64) {
            u64 k0 = keys[tid],       k1 = keys[tid + 64];
            u64 k2 = keys[tid + 128], k3 = keys[tid + 192];
            u64 ka = k0 < k1 ? k0 : k1;
            u64 kb = k2 < k3 ? k2 : k3;
            u64 kk = ka < kb ? ka : kb;            // windows ascending + u64 min
            int nearest = (int)(unsigned)(kk & 0xFFFFFFFFull);
            int n2 = ptile * 64 + tid;
            float cosv = cos_pm(sd0T, td0T, (size_t)b * N0 + n2,
                                (size_t)b * N0 + nearest);
            wave_reduce_atomic(cosv, acc + 0);
        }
    } else {
        int bb = bx - 256;
        int b = bb >> 1;
        const float4* tp = pt1 + b * N1;
        for (int i = tid; i < N1; i += 256)
            sm[i] = tp[i];                         // pre-transformed in pass2z
        __syncthreads();
        int n = (bb & 1) * 256 + tid;
        float4 P = ps1[b * N1 + n];
        float best = FLT_MAX; int bbase = 0;
        for (int k0 = 0; k0 < N1; k0 += 16) {
            float d[16];
#pragma unroll
            for (int u = 0; u < 16; ++u)
                d[u] = dist_pm(P, sm[k0 + u]);
            float e0 = fminf(d[0],  d[1]),  e1 = fminf(d[2],  d[3]);
            float e2 = fminf(d[4],  d[5]),  e3 = fminf(d[6],  d[7]);
            float e4 = fminf(d[8],  d[9]),  e5 = fminf(d[10], d[11]);
            float e6 = fminf(d[12], d[13]), e7 = fminf(d[14], d[15]);
            float f0 = fminf(e0, e1), f1 = fminf(e2, e3);
            float f2 = fminf(e4, e5), f3 = fminf(e6, e7);
            float bm = fminf(fminf(f0, f1), fminf(f2, f3));
            if (bm < best) { best = bm; bbase = k0; }
        }
        int bi = 0;
#pragma unroll
        for (int u = 15; u >= 0; --u) {
            float dv = dist_pm(P, sm[bbase + u]);
            if (dv == best) bi = u;
        }
        float cosv = cos_pm(sd1T, td1T, (size_t)b * N1 + n,
                            (size_t)b * N1 + bbase + bi);
        wave_reduce_atomic(cosv, acc + 1);
    }

    __syncthreads();                               // block's atomics all issued
    if (tid == 0) {
        __threadfence();
        unsigned old = atomicAdd((unsigned*)(acc + 2), 1u);
        if (old == 263u) {                         // last of 264 blocks
            float a0 = atomicAdd(acc + 0, 0.f);
            float a1 = atomicAdd(acc + 1, 0.f);
            out[0] = 1.f - 0.5f * (a0 * (1.f / 16384.f) + a1 * (1.f / 2048.f));
        }
    }
}

extern "C" void kernel_launch(void* const* d_in, const int* in_sizes, int n_in,
                              void* d_out, int out_size, void* d_ws, size_t ws_size,
                              hipStream_t stream) {
    const float* c_src = (const float*)d_in[0];   // [4,3,64,64,64]
    const float* c_tgt = (const float*)d_in[1];
    const float* sd0   = (const float*)d_in[2];   // [4,32,16,16,16]
    const float* td0   = (const float*)d_in[3];
    const float* sd1   = (const float*)d_in[4];   // [4,32,8,8,8]
    const float* td1   = (const float*)d_in[5];
    float* out = (float*)d_out;

    char* ws = (char*)d_ws;
    float* acc  = (float*)ws;                      // [0]=sum0 [1]=sum1 [2]=ticket
    float* x16a = (float*)(ws + 256);              // 196608 floats each [bc][z][16][16]
    float* x16b = x16a + 196608;
    float* x8a  = x16b + 196608;                   // 49152 floats each [bc][z][8][8]
    float* x8b  = x8a + 49152;
    float4* ps0 = (float4*)(x8b + 49152);          // 16384 float4
    float4* pt0 = ps0 + 16384;
    float4* ps1 = pt0 + 16384;                     // 2048 float4
    float4* pt1 = ps1 + 2048;
    float* sd0T = (float*)(pt1 + 2048);            // 524288 floats each
    float* td0T = sd0T + 524288;
    float* sd1T = td0T + 524288;                   // 65536 floats each
    float* td1T = sd1T + 65536;

    pass1_fused<<<dim3(1056, 2), 256, 0, stream>>>(c_src, c_tgt, sd0, td0, sd1, td1,
                                                   x16a, x16b, x8a, x8b,
                                                   sd0T, td0T, sd1T, td1T, acc);
    pass2z<<<144, 256, 0, stream>>>(x16a, x16b, x8a, x8b, ps0, pt0, ps1, pt1);
    nn_cos_all<<<264, 256, 65536, stream>>>(ps0, pt0, sd0T, td0T, ps1, pt1,
                                            sd1T, td1T, acc, out);
}

// Round 7
// 114.039 us; speedup vs baseline: 1.0867x; 1.0142x over previous
//
#include <hip/hip_runtime.h>
#include <cfloat>

typedef unsigned long long u64;

#define CDESC 32
#define N0 4096
#define N1 512

// sign-transformed float bits: monotone u32 over the float total order
__device__ __forceinline__ unsigned fbits_mono(float d) {
    unsigned b = __float_as_uint(d);
    return (d >= 0.f) ? (b | 0x80000000u) : ~b;
}

__device__ __forceinline__ void wave_reduce_atomic(float v, float* acc) {
#pragma unroll
    for (int off = 32; off > 0; off >>= 1) v += __shfl_down(v, off, 64);
    if ((threadIdx.x & 63) == 0) atomicAdd(acc, v);
}

// ======================= K1: fused x+y filter (both stages) + transpose =======================
// R13 (structure) + R14 (pad-index fix). sRow zero-padded to cols [-4,67]
// (stride 73, odd -> all tap reads <=2-way banked = free); xf16/xf8 zero-padded
// rows (strides 19/9). wsum from 2-entry LUT: edge sums (3.5/7.0) are exact fp
// sums of the same weights -> identical division bits; zero-pad taps add
// exactly 0 (fmaf(w,0,sum)=sum). Tap body = ds_read + fma only.
// R14 FIX: high pad rows were written at r+62/r+60 (data rows!) instead of
// r+64 -> y-filter edge outputs read uninitialized LDS (absmax 0.0039,
// nondeterministic). Correct mapping: xf16P rows {0,1,66,67} = r<2?r:r+64;
// xf8P rows {0..3,68..71} = r<4?r:r+64.
// blocks 0..767 (x2 sides): per-(channel,z)-plane x-filter then y-filter; only
// [16][16] and [8][8] outputs to HBM (verified R11 structure).
// blocks 768..1055: descriptor transpose [b][32][N] -> [b][N][32] (verified R7).
__global__ __launch_bounds__(256) void pass1_fused(
        const float* __restrict__ csrc, const float* __restrict__ ctgt,
        const float* __restrict__ sd0, const float* __restrict__ td0,
        const float* __restrict__ sd1, const float* __restrict__ td1,
        float* __restrict__ x16a, float* __restrict__ x16b,
        float* __restrict__ x8a,  float* __restrict__ x8b,
        float* __restrict__ sd0T, float* __restrict__ td0T,
        float* __restrict__ sd1T, float* __restrict__ td1T,
        float* __restrict__ acc) {
    __shared__ __align__(16) float lds[6612];
    float* sRowP = lds;            // [64][73], col 4+j for j in [-4,67]
    float* xf16P = lds + 4672;     // [68][19], row 2+j for j in [-2,65]
    float* xf8P  = lds + 5964;     // [72][9],  row 4+j for j in [-4,67]
    const int tid = threadIdx.x;
    const int bx  = blockIdx.x, by = blockIdx.y;
    if (by == 0 && bx == 0 && tid < 4) acc[tid] = 0.f;

    if (bx < 768) {
        int bc = bx >> 6, z = bx & 63;             // channel-plane, z-slice
        const float* in = by ? ctgt : csrc;
        float* o16 = by ? x16b : x16a;
        float* o8  = by ? x8b  : x8a;
        // ---- zero pads (parallel with staging, before first sync) ----
        if (tid < 512) {                           // sRowP: 8 pad cols x 64 rows
            int r = tid >> 3, c = tid & 7;
            sRowP[r * 73 + (c < 4 ? c : 64 + c)] = 0.f;
        }
        if (tid < 76) {                            // xf16P: rows 0,1,66,67 (R14 fix)
            int r = tid / 19, c = tid % 19;
            xf16P[(r < 2 ? r : r + 64) * 19 + c] = 0.f;
        }
        if (tid < 72) {                            // xf8P: rows 0..3, 68..71 (R14 fix)
            int r = tid / 9, c = tid % 9;
            xf8P[(r < 4 ? r : r + 64) * 9 + c] = 0.f;
        }
        const float4* src = (const float4*)(in + (size_t)(bc * 64 + z) * 4096);
#pragma unroll
        for (int k = 0; k < 4; ++k) {              // coalesced 16 KB stage, padded rows
            float4 v = src[tid + k * 256];
            int g = tid + k * 256;                 // float4 index 0..1023
            int y = g >> 4, j = (g & 15) * 4;      // row, col (scalar: 2-way banks)
            float* p = &sRowP[y * 73 + 4 + j];
            p[0] = v.x; p[1] = v.y; p[2] = v.z; p[3] = v.w;
        }
        __syncthreads();
#pragma unroll
        for (int k = 0; k < 6; ++k) {              // x-filter: 1536 vals, 6/thread
            int o = tid + k * 256;
            if (o < 1024) {                        // S=16, R=4 (k=0..3: no divergence)
                int y = o >> 4, xo = o & 15;
                const float* r = &sRowP[y * 73 + 4 * xo + 2];  // j0=4xo-2 -> col 4xo+2
                float sum = 0.f;
#pragma unroll
                for (int t = 0; t < 8; ++t) {
                    float w = 1.f - fabsf((float)t - 3.5f) * 0.25f;
                    sum = fmaf(w, r[t], sum);      // pads contribute exactly 0
                }
                float wsum = (xo == 0 || xo == 15) ? 3.5f : 4.0f;
                xf16P[(y + 2) * 19 + xo] = sum / wsum;
            } else {                               // S=8, R=8 (k=4,5)
                int o2 = o - 1024;
                int y = o2 >> 3, xo = o2 & 7;
                const float* r = &sRowP[y * 73 + 8 * xo];      // j0=8xo-4 -> col 8xo
                float sum = 0.f;
#pragma unroll
                for (int t = 0; t < 16; ++t) {
                    float w = 1.f - fabsf((float)t - 7.5f) * 0.125f;
                    sum = fmaf(w, r[t], sum);
                }
                float wsum = (xo == 0 || xo == 7) ? 7.f : 8.f;
                xf8P[(y + 4) * 9 + xo] = sum / wsum;
            }
        }
        __syncthreads();
        {                                          // y-filter S=16: 256 outs, 1/thread
            int y2 = tid >> 4, x = tid & 15;
            float sum = 0.f;
#pragma unroll
            for (int t = 0; t < 8; ++t) {          // rows 4y2-2+t -> padded 4y2+t
                float w = 1.f - fabsf((float)t - 3.5f) * 0.25f;
                sum = fmaf(w, xf16P[(4 * y2 + t) * 19 + x], sum);
            }
            float wsum = (y2 == 0 || y2 == 15) ? 3.5f : 4.0f;
            o16[bc * 16384 + z * 256 + y2 * 16 + x] = sum / wsum;  // coalesced 1 KB
        }
        if (tid < 64) {                            // y-filter S=8: 64 outs
            int y2 = tid >> 3, x = tid & 7;
            float sum = 0.f;
#pragma unroll
            for (int t = 0; t < 16; ++t) {         // rows 8y2-4+t -> padded 8y2+t
                float w = 1.f - fabsf((float)t - 7.5f) * 0.125f;
                sum = fmaf(w, xf8P[(8 * y2 + t) * 9 + x], sum);
            }
            float wsum = (y2 == 0 || y2 == 7) ? 7.f : 8.f;
            o8[bc * 4096 + z * 64 + y2 * 8 + x] = sum / wsum;      // coalesced 256 B
        }
    } else {
        // ---- transpose [b][32][N] -> [b][N][32], 64-point tiles (verified R7) ----
        float* tile = lds;                         // 64*33 = 2112 floats, fits overlay
        int tl = bx - 768;                         // 0..287
        const float* din; float* dout; int N, b, n0;
        if (tl < 256) { din = by ? td0 : sd0; dout = by ? td0T : sd0T;
                        N = N0; b = tl >> 6; n0 = (tl & 63) * 64; }
        else { tl -= 256; din = by ? td1 : sd1; dout = by ? td1T : sd1T;
               N = N1; b = tl >> 3; n0 = (tl & 7) * 64; }
#pragma unroll
        for (int i = 0; i < 8; ++i) {              // load: coalesced 64-float rows
            int idx = tid + i * 256;
            int c = idx >> 6, j = idx & 63;
            tile[j * 33 + c] = din[((size_t)b * CDESC + c) * N + n0 + j];
        }
        __syncthreads();
#pragma unroll
        for (int i = 0; i < 8; ++i) {              // store: contiguous 32-float points
            int idx = tid + i * 256;
            int p = idx >> 5, c = idx & 31;
            dout[((size_t)b * N + n0 + p) * CDESC + c] = tile[p * 33 + c];
        }
    }
}

// ======================= K2: z-filter only (both stages) =======================
// R11 (verified): pure 8-tap (S=16) / 16-tap (S=8) z-filter, coalesced 256 B
// reads per tap. Target side written PRE-TRANSFORMED (-2x,-2y,-2z,|t|^2).
__global__ __launch_bounds__(256) void pass2z(
        const float* __restrict__ x16a, const float* __restrict__ x16b,
        const float* __restrict__ x8a,  const float* __restrict__ x8b,
        float4* __restrict__ ps0, float4* __restrict__ pt0,
        float4* __restrict__ ps1, float4* __restrict__ pt1) {
    int gid = blockIdx.x * 256 + threadIdx.x;
    if (blockIdx.x < 128) {                        // stage-0: 32768 points
        int side = gid >> 14, r = gid & 16383;
        int b = r >> 12, n = r & 4095;
        int x = n & 15, y = (n >> 4) & 15, z = n >> 8;
        const float* t = side ? x16b : x16a;
        const float* base = t + (size_t)b * 49152 + y * 16 + x;  // b*3ch*16384
        float a0 = 0.f, a1 = 0.f, a2 = 0.f, wzs = 0.f;
#pragma unroll
        for (int tt = 0; tt < 8; ++tt) {
            float w = 1.f - fabsf((float)tt - 3.5f) * 0.25f;
            int jz = 4 * z - 2 + tt;
            if ((unsigned)jz < 64u) {
                const float* p = base + jz * 256;
                a0 = fmaf(w, p[0],     a0);
                a1 = fmaf(w, p[16384], a1);
                a2 = fmaf(w, p[32768], a2);
                wzs += w;
            }
        }
        float inv = 1.f / wzs;
        a0 *= inv; a1 *= inv; a2 *= inv;
        float sq = a0 * a0 + a1 * a1 + a2 * a2;
        if (side) pt0[b * N0 + n] = make_float4(-2.f * a0, -2.f * a1, -2.f * a2, sq);
        else      ps0[b * N0 + n] = make_float4(a0, a1, a2, sq);
    } else {                                       // stage-1: 4096 points
        int g = gid - 32768;
        int side = g >> 11, r = g & 2047;
        int b = r >> 9, n = r & 511;
        int x = n & 7, y = (n >> 3) & 7, z = n >> 6;
        const float* t = side ? x8b : x8a;
        const float* base = t + (size_t)b * 12288 + y * 8 + x;   // b*3ch*4096
        float a0 = 0.f, a1 = 0.f, a2 = 0.f, wzs = 0.f;
#pragma unroll
        for (int tt = 0; tt < 16; ++tt) {
            float w = 1.f - fabsf((float)tt - 7.5f) * 0.125f;
            int jz = 8 * z - 4 + tt;
            if ((unsigned)jz < 64u) {
                const float* p = base + jz * 64;
                a0 = fmaf(w, p[0],    a0);
                a1 = fmaf(w, p[4096], a1);
                a2 = fmaf(w, p[8192], a2);
                wzs += w;
            }
        }
        float inv = 1.f / wzs;
        a0 *= inv; a1 *= inv; a2 *= inv;
        float sq = a0 * a0 + a1 * a1 + a2 * a2;
        if (side) pt1[b * N1 + n] = make_float4(-2.f * a0, -2.f * a1, -2.f * a2, sq);
        else      ps1[b * N1 + n] = make_float4(a0, a1, a2, sq);
    }
}

// cosine of two point-major 32-float descriptors (coalesced float4 reads)
__device__ __forceinline__ float cos_pm(const float* __restrict__ sT,
                                        const float* __restrict__ tT,
                                        size_t si, size_t ti) {
    const float4* s = (const float4*)(sT + si * CDESC);
    const float4* t = (const float4*)(tT + ti * CDESC);
    float num = 0.f, s2 = 0.f, t2 = 0.f;
#pragma unroll
    for (int c = 0; c < 8; ++c) {
        float4 a = s[c], g = t[c];
        num = fmaf(a.x, g.x, fmaf(a.y, g.y, fmaf(a.z, g.z, fmaf(a.w, g.w, num))));
        s2  = fmaf(a.x, a.x, fmaf(a.y, a.y, fmaf(a.z, a.z, fmaf(a.w, a.w, s2))));
        t2  = fmaf(g.x, g.x, fmaf(g.y, g.y, fmaf(g.z, g.z, fmaf(g.w, g.w, t2))));
    }
    return num / (fmaxf(sqrtf(s2), 1e-8f) * fmaxf(sqrtf(t2), 1e-8f));
}

// d2 (minus the constant |s|^2 term) from a point P and a pre-transformed candidate Q
__device__ __forceinline__ float dist_pm(float4 P, float4 Q) {
    return fmaf(P.x, Q.x, fmaf(P.y, Q.y, fmaf(P.z, Q.z, Q.w)));
}

// ======================= K3: argmin + cosine (R3 measured-best body) =======================
// LDS-staged candidates (pure float4 copy; pre-transformed in pass2z), batch-16
// min-tree (chain-free) + strict-< batch compare + descending first-match re-scan
// == jnp.argmin first-min, bit-exact. 4 waves x 1024-candidate windows; combine
// via packed (mono(d)<<32|m) u64 keys in reused LDS. 264-ticket finalizer.
// (R10 SMEM and R12 readlane variants both measured SLOWER -- uniform-address
// ds_read_b128 broadcast is the fastest candidate path on this part.)
__global__ __launch_bounds__(256) void nn_cos_all(
        const float4* __restrict__ ps0, const float4* __restrict__ pt0,
        const float* __restrict__ sd0T, const float* __restrict__ td0T,
        const float4* __restrict__ ps1, const float4* __restrict__ pt1,
        const float* __restrict__ sd1T, const float* __restrict__ td1T,
        float* acc, float* __restrict__ out) {
    extern __shared__ __align__(16) char smraw[];  // 64 KB dynamic
    float4* sm = (float4*)smraw;
    const int tid = threadIdx.x;
    const int bx  = blockIdx.x;

    if (bx < 256) {
        int b = bx >> 6, ptile = bx & 63;
        const float4* tp = pt0 + b * N0;
        for (int i = tid; i < N0; i += 256)        // stage all 4096 targets (64 KB)
            sm[i] = tp[i];                         // pre-transformed in pass2z
        __syncthreads();
        int w = tid >> 6, lane = tid & 63;
        int n = ptile * 64 + lane;
        float4 P = ps0[b * N0 + n];
        const int m0 = w * 1024;                   // this wave's m-window
        float best = FLT_MAX; int bbase = 0;
        for (int k0 = 0; k0 < 1024; k0 += 16) {
            float d[16];
#pragma unroll
            for (int u = 0; u < 16; ++u)
                d[u] = dist_pm(P, sm[m0 + k0 + u]);  // broadcast, conflict-free
            float e0 = fminf(d[0],  d[1]),  e1 = fminf(d[2],  d[3]);
            float e2 = fminf(d[4],  d[5]),  e3 = fminf(d[6],  d[7]);
            float e4 = fminf(d[8],  d[9]),  e5 = fminf(d[10], d[11]);
            float e6 = fminf(d[12], d[13]), e7 = fminf(d[14], d[15]);
            float f0 = fminf(e0, e1), f1 = fminf(e2, e3);
            float f2 = fminf(e4, e5), f3 = fminf(e6, e7);
            float bm = fminf(fminf(f0, f1), fminf(f2, f3));
            if (bm < best) { best = bm; bbase = k0; }  // strict <: keeps first batch
        }
        int bi = 0;
#pragma unroll
        for (int u = 15; u >= 0; --u) {            // descending: ends at FIRST match
            float dv = dist_pm(P, sm[m0 + bbase + u]);
            if (dv == best) bi = u;
        }
        u64 key = ((u64)fbits_mono(best) << 32) | (unsigned)(m0 + bbase + bi);
        __syncthreads();                           // everyone done reading sm
        u64* keys = (u64*)smraw;                   // reuse LDS for combine
        keys[w * 64 + lane] = key;
        __syncthreads();
        if (tid < 64) {
            u64 k0 = keys[tid],       k1 = keys[tid + 64];
            u64 k2 = keys[tid + 128], k3 = keys[tid + 192];
            u64 ka = k0 < k1 ? k0 : k1;
            u64 kb = k2 < k3 ? k2 : k3;
            u64 kk = ka < kb ? ka : kb;            // windows ascending + u64 min
            int nearest = (int)(unsigned)(kk & 0xFFFFFFFFull);
            int n2 = ptile * 64 + tid;
            float cosv = cos_pm(sd0T, td0T, (size_t)b * N0 + n2,
                                (size_t)b * N0 + nearest);
            wave_reduce_atomic(cosv, acc + 0);
        }
    } else {
        int bb = bx - 256;
        int b = bb >> 1;
        const float4* tp = pt1 + b * N1;
        for (int i = tid; i < N1; i += 256)
            sm[i] = tp[i];                         // pre-transformed in pass2z
        __syncthreads();
        int n = (bb & 1) * 256 + tid;
        float4 P = ps1[b * N1 + n];
        float best = FLT_MAX; int bbase = 0;
        for (int k0 = 0; k0 < N1; k0 += 16) {
            float d[16];
#pragma unroll
            for (int u = 0; u < 16; ++u)
                d[u] = dist_pm(P, sm[k0 + u]);
            float e0 = fminf(d[0],  d[1]),  e1 = fminf(d[2],  d[3]);
            float e2 = fminf(d[4],  d[5]),  e3 = fminf(d[6],  d[7]);
            float e4 = fminf(d[8],  d[9]),  e5 = fminf(d[10], d[11]);
            float e6 = fminf(d[12], d[13]), e7 = fminf(d[14], d[15]);
            float f0 = fminf(e0, e1), f1 = fminf(e2, e3);
            float f2 = fminf(e4, e5), f3 = fminf(e6, e7);
            float bm = fminf(fminf(f0, f1), fminf(f2, f3));
            if (bm < best) { best = bm; bbase = k0; }
        }
        int bi = 0;
#pragma unroll
        for (int u = 15; u >= 0; --u) {
            float dv = dist_pm(P, sm[bbase + u]);
            if (dv == best) bi = u;
        }
        float cosv = cos_pm(sd1T, td1T, (size_t)b * N1 + n,
                            (size_t)b * N1 + bbase + bi);
        wave_reduce_atomic(cosv, acc + 1);
    }

    __syncthreads();                               // block's atomics all issued
    if (tid == 0) {
        __threadfence();
        unsigned old = atomicAdd((unsigned*)(acc + 2), 1u);
        if (old == 263u) {                         // last of 264 blocks
            float a0 = atomicAdd(acc + 0, 0.f);
            float a1 = atomicAdd(acc + 1, 0.f);
            out[0] = 1.f - 0.5f * (a0 * (1.f / 16384.f) + a1 * (1.f / 2048.f));
        }
    }
}

extern "C" void kernel_launch(void* const* d_in, const int* in_sizes, int n_in,
                              void* d_out, int out_size, void* d_ws, size_t ws_size,
                              hipStream_t stream) {
    const float* c_src = (const float*)d_in[0];   // [4,3,64,64,64]
    const float* c_tgt = (const float*)d_in[1];
    const float* sd0   = (const float*)d_in[2];   // [4,32,16,16,16]
    const float* td0   = (const float*)d_in[3];
    const float* sd1   = (const float*)d_in[4];   // [4,32,8,8,8]
    const float* td1   = (const float*)d_in[5];
    float* out = (float*)d_out;

    char* ws = (char*)d_ws;
    float* acc  = (float*)ws;                      // [0]=sum0 [1]=sum1 [2]=ticket
    float* x16a = (float*)(ws + 256);              // 196608 floats each [bc][z][16][16]
    float* x16b = x16a + 196608;
    float* x8a  = x16b + 196608;                   // 49152 floats each [bc][z][8][8]
    float* x8b  = x8a + 49152;
    float4* ps0 = (float4*)(x8b + 49152);          // 16384 float4
    float4* pt0 = ps0 + 16384;
    float4* ps1 = pt0 + 16384;                     // 2048 float4
    float4* pt1 = ps1 + 2048;
    float* sd0T = (float*)(pt1 + 2048);            // 524288 floats each
    float* td0T = sd0T + 524288;
    float* sd1T = td0T + 524288;                   // 65536 floats each
    float* td1T = sd1T + 65536;

    pass1_fused<<<dim3(1056, 2), 256, 0, stream>>>(c_src, c_tgt, sd0, td0, sd1, td1,
                                                   x16a, x16b, x8a, x8b,
                                                   sd0T, td0T, sd1T, td1T, acc);
    pass2z<<<144, 256, 0, stream>>>(x16a, x16b, x8a, x8b, ps0, pt0, ps1, pt1);
    nn_cos_all<<<264, 256, 65536, stream>>>(ps0, pt0, sd0T, td0T, ps1, pt1,
                                            sd1T, td1T, acc, out);
}

// Round 9
// 111.706 us; speedup vs baseline: 1.1094x; 1.0209x over previous
//
#include <hip/hip_runtime.h>
#include <cfloat>

typedef unsigned long long u64;

#define CDESC 32
#define N0 4096
#define N1 512

// sign-transformed float bits: monotone u32 over the float total order
__device__ __forceinline__ unsigned fbits_mono(float d) {
    unsigned b = __float_as_uint(d);
    return (d >= 0.f) ? (b | 0x80000000u) : ~b;
}

__device__ __forceinline__ void wave_reduce_atomic(float v, float* acc) {
#pragma unroll
    for (int off = 32; off > 0; off >>= 1) v += __shfl_down(v, off, 64);
    if ((threadIdx.x & 63) == 0) atomicAdd(acc, v);
}

// ======================= K1: fused x+y filter (both stages) + transpose =======================
// R13 structure + R14 pad fix (verified bit-exact, measured best).
__global__ __launch_bounds__(256) void pass1_fused(
        const float* __restrict__ csrc, const float* __restrict__ ctgt,
        const float* __restrict__ sd0, const float* __restrict__ td0,
        const float* __restrict__ sd1, const float* __restrict__ td1,
        float* __restrict__ x16a, float* __restrict__ x16b,
        float* __restrict__ x8a,  float* __restrict__ x8b,
        float* __restrict__ sd0T, float* __restrict__ td0T,
        float* __restrict__ sd1T, float* __restrict__ td1T,
        float* __restrict__ acc) {
    __shared__ __align__(16) float lds[6612];
    float* sRowP = lds;            // [64][73], col 4+j for j in [-4,67]
    float* xf16P = lds + 4672;     // [68][19], row 2+j for j in [-2,65]
    float* xf8P  = lds + 5964;     // [72][9],  row 4+j for j in [-4,67]
    const int tid = threadIdx.x;
    const int bx  = blockIdx.x, by = blockIdx.y;
    if (by == 0 && bx == 0 && tid < 4) acc[tid] = 0.f;

    if (bx < 768) {
        int bc = bx >> 6, z = bx & 63;             // channel-plane, z-slice
        const float* in = by ? ctgt : csrc;
        float* o16 = by ? x16b : x16a;
        float* o8  = by ? x8b  : x8a;
        // ---- zero pads (parallel with staging, before first sync) ----
        if (tid < 512) {                           // sRowP: 8 pad cols x 64 rows
            int r = tid >> 3, c = tid & 7;
            sRowP[r * 73 + (c < 4 ? c : 64 + c)] = 0.f;
        }
        if (tid < 76) {                            // xf16P: rows 0,1,66,67
            int r = tid / 19, c = tid % 19;
            xf16P[(r < 2 ? r : r + 64) * 19 + c] = 0.f;
        }
        if (tid < 72) {                            // xf8P: rows 0..3, 68..71
            int r = tid / 9, c = tid % 9;
            xf8P[(r < 4 ? r : r + 64) * 9 + c] = 0.f;
        }
        const float4* src = (const float4*)(in + (size_t)(bc * 64 + z) * 4096);
#pragma unroll
        for (int k = 0; k < 4; ++k) {              // coalesced 16 KB stage, padded rows
            float4 v = src[tid + k * 256];
            int g = tid + k * 256;                 // float4 index 0..1023
            int y = g >> 4, j = (g & 15) * 4;      // row, col (scalar: 2-way banks)
            float* p = &sRowP[y * 73 + 4 + j];
            p[0] = v.x; p[1] = v.y; p[2] = v.z; p[3] = v.w;
        }
        __syncthreads();
#pragma unroll
        for (int k = 0; k < 6; ++k) {              // x-filter: 1536 vals, 6/thread
            int o = tid + k * 256;
            if (o < 1024) {                        // S=16, R=4 (k=0..3: no divergence)
                int y = o >> 4, xo = o & 15;
                const float* r = &sRowP[y * 73 + 4 * xo + 2];  // j0=4xo-2 -> col 4xo+2
                float sum = 0.f;
#pragma unroll
                for (int t = 0; t < 8; ++t) {
                    float w = 1.f - fabsf((float)t - 3.5f) * 0.25f;
                    sum = fmaf(w, r[t], sum);      // pads contribute exactly 0
                }
                float wsum = (xo == 0 || xo == 15) ? 3.5f : 4.0f;
                xf16P[(y + 2) * 19 + xo] = sum / wsum;
            } else {                               // S=8, R=8 (k=4,5)
                int o2 = o - 1024;
                int y = o2 >> 3, xo = o2 & 7;
                const float* r = &sRowP[y * 73 + 8 * xo];      // j0=8xo-4 -> col 8xo
                float sum = 0.f;
#pragma unroll
                for (int t = 0; t < 16; ++t) {
                    float w = 1.f - fabsf((float)t - 7.5f) * 0.125f;
                    sum = fmaf(w, r[t], sum);
                }
                float wsum = (xo == 0 || xo == 7) ? 7.f : 8.f;
                xf8P[(y + 4) * 9 + xo] = sum / wsum;
            }
        }
        __syncthreads();
        {                                          // y-filter S=16: 256 outs, 1/thread
            int y2 = tid >> 4, x = tid & 15;
            float sum = 0.f;
#pragma unroll
            for (int t = 0; t < 8; ++t) {          // rows 4y2-2+t -> padded 4y2+t
                float w = 1.f - fabsf((float)t - 3.5f) * 0.25f;
                sum = fmaf(w, xf16P[(4 * y2 + t) * 19 + x], sum);
            }
            float wsum = (y2 == 0 || y2 == 15) ? 3.5f : 4.0f;
            o16[bc * 16384 + z * 256 + y2 * 16 + x] = sum / wsum;  // coalesced 1 KB
        }
        if (tid < 64) {                            // y-filter S=8: 64 outs
            int y2 = tid >> 3, x = tid & 7;
            float sum = 0.f;
#pragma unroll
            for (int t = 0; t < 16; ++t) {         // rows 8y2-4+t -> padded 8y2+t
                float w = 1.f - fabsf((float)t - 7.5f) * 0.125f;
                sum = fmaf(w, xf8P[(8 * y2 + t) * 9 + x], sum);
            }
            float wsum = (y2 == 0 || y2 == 7) ? 7.f : 8.f;
            o8[bc * 4096 + z * 64 + y2 * 8 + x] = sum / wsum;      // coalesced 256 B
        }
    } else {
        // ---- transpose [b][32][N] -> [b][N][32], 64-point tiles (verified R7) ----
        float* tile = lds;                         // 64*33 = 2112 floats, fits overlay
        int tl = bx - 768;                         // 0..287
        const float* din; float* dout; int N, b, n0;
        if (tl < 256) { din = by ? td0 : sd0; dout = by ? td0T : sd0T;
                        N = N0; b = tl >> 6; n0 = (tl & 63) * 64; }
        else { tl -= 256; din = by ? td1 : sd1; dout = by ? td1T : sd1T;
               N = N1; b = tl >> 3; n0 = (tl & 7) * 64; }
#pragma unroll
        for (int i = 0; i < 8; ++i) {              // load: coalesced 64-float rows
            int idx = tid + i * 256;
            int c = idx >> 6, j = idx & 63;
            tile[j * 33 + c] = din[((size_t)b * CDESC + c) * N + n0 + j];
        }
        __syncthreads();
#pragma unroll
        for (int i = 0; i < 8; ++i) {              // store: contiguous 32-float points
            int idx = tid + i * 256;
            int p = idx >> 5, c = idx & 31;
            dout[((size_t)b * N + n0 + p) * CDESC + c] = tile[p * 33 + c];
        }
    }
}

// ======================= K2: z-filter only (both stages) =======================
// R11 (verified). R15: also initializes K3's cross-block argmin state
// (gkeys sentinels + group tickets) -- stream order guarantees visibility.
__global__ __launch_bounds__(256) void pass2z(
        const float* __restrict__ x16a, const float* __restrict__ x16b,
        const float* __restrict__ x8a,  const float* __restrict__ x8b,
        float4* __restrict__ ps0, float4* __restrict__ pt0,
        float4* __restrict__ ps1, float4* __restrict__ pt1,
        u64* __restrict__ gkeys, unsigned* __restrict__ gtick) {
    int gid = blockIdx.x * 256 + threadIdx.x;
    if (gid < 16384) gkeys[gid] = ~0ull;           // argmin sentinels (stage-0)
    else if (gid < 16448) gtick[gid - 16384] = 0u; // 64 group tickets
    if (blockIdx.x < 128) {                        // stage-0: 32768 points
        int side = gid >> 14, r = gid & 16383;
        int b = r >> 12, n = r & 4095;
        int x = n & 15, y = (n >> 4) & 15, z = n >> 8;
        const float* t = side ? x16b : x16a;
        const float* base = t + (size_t)b * 49152 + y * 16 + x;  // b*3ch*16384
        float a0 = 0.f, a1 = 0.f, a2 = 0.f, wzs = 0.f;
#pragma unroll
        for (int tt = 0; tt < 8; ++tt) {
            float w = 1.f - fabsf((float)tt - 3.5f) * 0.25f;
            int jz = 4 * z - 2 + tt;
            if ((unsigned)jz < 64u) {
                const float* p = base + jz * 256;
                a0 = fmaf(w, p[0],     a0);
                a1 = fmaf(w, p[16384], a1);
                a2 = fmaf(w, p[32768], a2);
                wzs += w;
            }
        }
        float inv = 1.f / wzs;
        a0 *= inv; a1 *= inv; a2 *= inv;
        float sq = a0 * a0 + a1 * a1 + a2 * a2;
        if (side) pt0[b * N0 + n] = make_float4(-2.f * a0, -2.f * a1, -2.f * a2, sq);
        else      ps0[b * N0 + n] = make_float4(a0, a1, a2, sq);
    } else {                                       // stage-1: 4096 points
        int g = gid - 32768;
        int side = g >> 11, r = g & 2047;
        int b = r >> 9, n = r & 511;
        int x = n & 7, y = (n >> 3) & 7, z = n >> 6;
        const float* t = side ? x8b : x8a;
        const float* base = t + (size_t)b * 12288 + y * 8 + x;   // b*3ch*4096
        float a0 = 0.f, a1 = 0.f, a2 = 0.f, wzs = 0.f;
#pragma unroll
        for (int tt = 0; tt < 16; ++tt) {
            float w = 1.f - fabsf((float)tt - 7.5f) * 0.125f;
            int jz = 8 * z - 4 + tt;
            if ((unsigned)jz < 64u) {
                const float* p = base + jz * 64;
                a0 = fmaf(w, p[0],    a0);
                a1 = fmaf(w, p[4096], a1);
                a2 = fmaf(w, p[8192], a2);
                wzs += w;
            }
        }
        float inv = 1.f / wzs;
        a0 *= inv; a1 *= inv; a2 *= inv;
        float sq = a0 * a0 + a1 * a1 + a2 * a2;
        if (side) pt1[b * N1 + n] = make_float4(-2.f * a0, -2.f * a1, -2.f * a2, sq);
        else      ps1[b * N1 + n] = make_float4(a0, a1, a2, sq);
    }
}

// cosine of two point-major 32-float descriptors (coalesced float4 reads)
__device__ __forceinline__ float cos_pm(const float* __restrict__ sT,
                                        const float* __restrict__ tT,
                                        size_t si, size_t ti) {
    const float4* s = (const float4*)(sT + si * CDESC);
    const float4* t = (const float4*)(tT + ti * CDESC);
    float num = 0.f, s2 = 0.f, t2 = 0.f;
#pragma unroll
    for (int c = 0; c < 8; ++c) {
        float4 a = s[c], g = t[c];
        num = fmaf(a.x, g.x, fmaf(a.y, g.y, fmaf(a.z, g.z, fmaf(a.w, g.w, num))));
        s2  = fmaf(a.x, a.x, fmaf(a.y, a.y, fmaf(a.z, a.z, fmaf(a.w, a.w, s2))));
        t2  = fmaf(g.x, g.x, fmaf(g.y, g.y, fmaf(g.z, g.z, fmaf(g.w, g.w, t2))));
    }
    return num / (fmaxf(sqrtf(s2), 1e-8f) * fmaxf(sqrtf(t2), 1e-8f));
}

// d2 (minus the constant |s|^2 term) from a point P and a pre-transformed candidate Q
__device__ __forceinline__ float dist_pm(float4 P, float4 Q) {
    return fmaf(P.x, Q.x, fmaf(P.y, Q.y, fmaf(P.z, Q.z, Q.w)));
}

// ======================= K3: argmin + cosine =======================
// R15: candidate-SPLIT stage-0. The old per-block full-scan paid 4096 broadcast
// ds_read_b128 serialized on the CU's single DS pipe (~49K cyc/block) -- the
// structural wall. Now block=(b, 256-pt group g, candidate-quarter q): stages
// 1024 candidates (16 KB LDS), 4 waves x 256-cand windows, 4 points/lane
// (independent compare chains = ILP). DS/block = 1024 reads (~12K cyc),
// VALU-balanced. Exactness: per-window strict-< ascending scan keeps first-min;
// cross-window/cross-block combine via u64 key = (mono(d)<<32 | m) and global
// atomicMin == lexicographic (d,m) min == jnp.argmin first-min; d bits
// identical (same fmaf chain on same staged values). 4th-arriving block per
// group (ticket) computes the 256 cosines; atomic reads bypass stale L1.
// blocks 256..263: stage-1 (R3 verified body). 264-ticket finalizer unchanged.
__global__ __launch_bounds__(256) void nn_cos_all(
        const float4* __restrict__ ps0, const float4* __restrict__ pt0,
        const float* __restrict__ sd0T, const float* __restrict__ td0T,
        const float4* __restrict__ ps1, const float4* __restrict__ pt1,
        const float* __restrict__ sd1T, const float* __restrict__ td1T,
        u64* __restrict__ gkeys, unsigned* __restrict__ gtick,
        float* acc, float* __restrict__ out) {
    extern __shared__ __align__(16) char smraw[];  // 24 KB dynamic
    float4* sm = (float4*)smraw;
    __shared__ unsigned sflag;
    const int tid = threadIdx.x;
    const int bx  = blockIdx.x;

    if (bx < 256) {
        int b = bx >> 6, g = (bx >> 2) & 15, q = bx & 3;
        const float4* tp = pt0 + b * N0 + q * 1024;
        for (int i = tid; i < 1024; i += 256)      // stage this quarter (16 KB)
            sm[i] = tp[i];                         // pre-transformed in pass2z
        int lane = tid & 63, w = tid >> 6;
        int pbase = b * N0 + g * 256 + lane;
        float4 P0 = ps0[pbase];
        float4 P1 = ps0[pbase + 64];
        float4 P2 = ps0[pbase + 128];
        float4 P3 = ps0[pbase + 192];
        __syncthreads();
        const int m0 = w * 256;                    // this wave's window in the quarter
        float b0 = FLT_MAX, b1 = FLT_MAX, b2 = FLT_MAX, b3 = FLT_MAX;
        int i0 = 0, i1 = 0, i2 = 0, i3 = 0;
#pragma unroll 8
        for (int k = 0; k < 256; ++k) {
            float4 Q = sm[m0 + k];                 // broadcast, conflict-free
            float d0 = dist_pm(P0, Q);
            float d1 = dist_pm(P1, Q);
            float d2 = dist_pm(P2, Q);
            float d3 = dist_pm(P3, Q);
            if (d0 < b0) { b0 = d0; i0 = k; }      // ascending k: first-min
            if (d1 < b1) { b1 = d1; i1 = k; }
            if (d2 < b2) { b2 = d2; i2 = k; }
            if (d3 < b3) { b3 = d3; i3 = k; }
        }
        int mb = q * 1024 + m0;                    // global m of window base
        u64* keys = (u64*)(smraw + 16384);         // 8 KB key region after sm
        keys[w * 256 + lane      ] = ((u64)fbits_mono(b0) << 32) | (unsigned)(mb + i0);
        keys[w * 256 + lane + 64 ] = ((u64)fbits_mono(b1) << 32) | (unsigned)(mb + i1);
        keys[w * 256 + lane + 128] = ((u64)fbits_mono(b2) << 32) | (unsigned)(mb + i2);
        keys[w * 256 + lane + 192] = ((u64)fbits_mono(b3) << 32) | (unsigned)(mb + i3);
        __syncthreads();
        {                                          // combine 4 windows, point p=tid
            u64 k0 = keys[tid],       k1 = keys[256 + tid];
            u64 k2 = keys[512 + tid], k3 = keys[768 + tid];
            u64 ka = k0 < k1 ? k0 : k1;
            u64 kb = k2 < k3 ? k2 : k3;
            u64 kk = ka < kb ? ka : kb;
            atomicMin(&gkeys[(size_t)b * N0 + g * 256 + tid], kk);
        }
        __syncthreads();                           // barrier drains all atomics (vmcnt 0)
        if (tid == 0) sflag = atomicAdd(&gtick[b * 16 + g], 1u);
        __syncthreads();
        if (sflag == 3u) {                         // last of the group's 4 quarters
            u64 kk = atomicAdd(&gkeys[(size_t)b * N0 + g * 256 + tid], 0ull);  // L2 read
            int nearest = (int)(unsigned)(kk & 0xFFFFFFFFull);
            int n2 = g * 256 + tid;
            float cosv = cos_pm(sd0T, td0T, (size_t)b * N0 + n2,
                                (size_t)b * N0 + nearest);
            wave_reduce_atomic(cosv, acc + 0);
        }
    } else {
        int bb = bx - 256;
        int b = bb >> 1;
        const float4* tp = pt1 + b * N1;
        for (int i = tid; i < N1; i += 256)
            sm[i] = tp[i];                         // pre-transformed in pass2z
        __syncthreads();
        int n = (bb & 1) * 256 + tid;
        float4 P = ps1[b * N1 + n];
        float best = FLT_MAX; int bbase = 0;
        for (int k0 = 0; k0 < N1; k0 += 16) {
            float d[16];
#pragma unroll
            for (int u = 0; u < 16; ++u)
                d[u] = dist_pm(P, sm[k0 + u]);
            float e0 = fminf(d[0],  d[1]),  e1 = fminf(d[2],  d[3]);
            float e2 = fminf(d[4],  d[5]),  e3 = fminf(d[6],  d[7]);
            float e4 = fminf(d[8],  d[9]),  e5 = fminf(d[10], d[11]);
            float e6 = fminf(d[12], d[13]), e7 = fminf(d[14], d[15]);
            float f0 = fminf(e0, e1), f1 = fminf(e2, e3);
            float f2 = fminf(e4, e5), f3 = fminf(e6, e7);
            float bm = fminf(fminf(f0, f1), fminf(f2, f3));
            if (bm < best) { best = bm; bbase = k0; }
        }
        int bi = 0;
#pragma unroll
        for (int u = 15; u >= 0; --u) {            // descending: ends at FIRST match
            float dv = dist_pm(P, sm[bbase + u]);
            if (dv == best) bi = u;
        }
        float cosv = cos_pm(sd1T, td1T, (size_t)b * N1 + n,
                            (size_t)b * N1 + bbase + bi);
        wave_reduce_atomic(cosv, acc + 1);
    }

    __syncthreads();                               // block's atomics all issued
    if (tid == 0) {
        __threadfence();
        unsigned old = atomicAdd((unsigned*)(acc + 2), 1u);
        if (old == 263u) {                         // last of 264 blocks
            float a0 = atomicAdd(acc + 0, 0.f);
            float a1 = atomicAdd(acc + 1, 0.f);
            out[0] = 1.f - 0.5f * (a0 * (1.f / 16384.f) + a1 * (1.f / 2048.f));
        }
    }
}

extern "C" void kernel_launch(void* const* d_in, const int* in_sizes, int n_in,
                              void* d_out, int out_size, void* d_ws, size_t ws_size,
                              hipStream_t stream) {
    const float* c_src = (const float*)d_in[0];   // [4,3,64,64,64]
    const float* c_tgt = (const float*)d_in[1];
    const float* sd0   = (const float*)d_in[2];   // [4,32,16,16,16]
    const float* td0   = (const float*)d_in[3];
    const float* sd1   = (const float*)d_in[4];   // [4,32,8,8,8]
    const float* td1   = (const float*)d_in[5];
    float* out = (float*)d_out;

    char* ws = (char*)d_ws;
    float* acc  = (float*)ws;                      // [0]=sum0 [1]=sum1 [2]=ticket
    float* x16a = (float*)(ws + 256);              // 196608 floats each [bc][z][16][16]
    float* x16b = x16a + 196608;
    float* x8a  = x16b + 196608;                   // 49152 floats each [bc][z][8][8]
    float* x8b  = x8a + 49152;
    float4* ps0 = (float4*)(x8b + 49152);          // 16384 float4
    float4* pt0 = ps0 + 16384;
    float4* ps1 = pt0 + 16384;                     // 2048 float4
    float4* pt1 = ps1 + 2048;
    float* sd0T = (float*)(pt1 + 2048);            // 524288 floats each
    float* td0T = sd0T + 524288;
    float* sd1T = td0T + 524288;                   // 65536 floats each
    float* td1T = sd1T + 65536;
    u64* gkeys  = (u64*)(td1T + 65536);            // 16384 u64 partial-argmin keys
    unsigned* gtick = (unsigned*)(gkeys + 16384);  // 64 group tickets

    pass1_fused<<<dim3(1056, 2), 256, 0, stream>>>(c_src, c_tgt, sd0, td0, sd1, td1,
                                                   x16a, x16b, x8a, x8b,
                                                   sd0T, td0T, sd1T, td1T, acc);
    pass2z<<<144, 256, 0, stream>>>(x16a, x16b, x8a, x8b, ps0, pt0, ps1, pt1,
                                    gkeys, gtick);
    nn_cos_all<<<264, 256, 24576, stream>>>(ps0, pt0, sd0T, td0T, ps1, pt1,
                                            sd1T, td1T, gkeys, gtick, acc, out);
}

// Round 10
// 109.754 us; speedup vs baseline: 1.1291x; 1.0178x over previous
//
#include <hip/hip_runtime.h>
#include <cfloat>

typedef unsigned long long u64;

#define CDESC 32
#define N0 4096
#define N1 512

// sign-transformed float bits: monotone u32 over the float total order
__device__ __forceinline__ unsigned fbits_mono(float d) {
    unsigned b = __float_as_uint(d);
    return (d >= 0.f) ? (b | 0x80000000u) : ~b;
}

__device__ __forceinline__ void wave_reduce_atomic(float v, float* acc) {
#pragma unroll
    for (int off = 32; off > 0; off >>= 1) v += __shfl_down(v, off, 64);
    if ((threadIdx.x & 63) == 0) atomicAdd(acc, v);
}

// ======================= K1: fused x+y filter (both stages) + transpose =======================
// R13 structure + R14 pad fix (verified bit-exact, measured best).
__global__ __launch_bounds__(256) void pass1_fused(
        const float* __restrict__ csrc, const float* __restrict__ ctgt,
        const float* __restrict__ sd0, const float* __restrict__ td0,
        const float* __restrict__ sd1, const float* __restrict__ td1,
        float* __restrict__ x16a, float* __restrict__ x16b,
        float* __restrict__ x8a,  float* __restrict__ x8b,
        float* __restrict__ sd0T, float* __restrict__ td0T,
        float* __restrict__ sd1T, float* __restrict__ td1T,
        float* __restrict__ acc) {
    __shared__ __align__(16) float lds[6612];
    float* sRowP = lds;            // [64][73], col 4+j for j in [-4,67]
    float* xf16P = lds + 4672;     // [68][19], row 2+j for j in [-2,65]
    float* xf8P  = lds + 5964;     // [72][9],  row 4+j for j in [-4,67]
    const int tid = threadIdx.x;
    const int bx  = blockIdx.x, by = blockIdx.y;
    if (by == 0 && bx == 0 && tid < 4) acc[tid] = 0.f;

    if (bx < 768) {
        int bc = bx >> 6, z = bx & 63;             // channel-plane, z-slice
        const float* in = by ? ctgt : csrc;
        float* o16 = by ? x16b : x16a;
        float* o8  = by ? x8b  : x8a;
        // ---- zero pads (parallel with staging, before first sync) ----
        if (tid < 512) {                           // sRowP: 8 pad cols x 64 rows
            int r = tid >> 3, c = tid & 7;
            sRowP[r * 73 + (c < 4 ? c : 64 + c)] = 0.f;
        }
        if (tid < 76) {                            // xf16P: rows 0,1,66,67
            int r = tid / 19, c = tid % 19;
            xf16P[(r < 2 ? r : r + 64) * 19 + c] = 0.f;
        }
        if (tid < 72) {                            // xf8P: rows 0..3, 68..71
            int r = tid / 9, c = tid % 9;
            xf8P[(r < 4 ? r : r + 64) * 9 + c] = 0.f;
        }
        const float4* src = (const float4*)(in + (size_t)(bc * 64 + z) * 4096);
#pragma unroll
        for (int k = 0; k < 4; ++k) {              // coalesced 16 KB stage, padded rows
            float4 v = src[tid + k * 256];
            int g = tid + k * 256;                 // float4 index 0..1023
            int y = g >> 4, j = (g & 15) * 4;      // row, col (scalar: 2-way banks)
            float* p = &sRowP[y * 73 + 4 + j];
            p[0] = v.x; p[1] = v.y; p[2] = v.z; p[3] = v.w;
        }
        __syncthreads();
#pragma unroll
        for (int k = 0; k < 6; ++k) {              // x-filter: 1536 vals, 6/thread
            int o = tid + k * 256;
            if (o < 1024) {                        // S=16, R=4 (k=0..3: no divergence)
                int y = o >> 4, xo = o & 15;
                const float* r = &sRowP[y * 73 + 4 * xo + 2];  // j0=4xo-2 -> col 4xo+2
                float sum = 0.f;
#pragma unroll
                for (int t = 0; t < 8; ++t) {
                    float w = 1.f - fabsf((float)t - 3.5f) * 0.25f;
                    sum = fmaf(w, r[t], sum);      // pads contribute exactly 0
                }
                float wsum = (xo == 0 || xo == 15) ? 3.5f : 4.0f;
                xf16P[(y + 2) * 19 + xo] = sum / wsum;
            } else {                               // S=8, R=8 (k=4,5)
                int o2 = o - 1024;
                int y = o2 >> 3, xo = o2 & 7;
                const float* r = &sRowP[y * 73 + 8 * xo];      // j0=8xo-4 -> col 8xo
                float sum = 0.f;
#pragma unroll
                for (int t = 0; t < 16; ++t) {
                    float w = 1.f - fabsf((float)t - 7.5f) * 0.125f;
                    sum = fmaf(w, r[t], sum);
                }
                float wsum = (xo == 0 || xo == 7) ? 7.f : 8.f;
                xf8P[(y + 4) * 9 + xo] = sum / wsum;
            }
        }
        __syncthreads();
        {                                          // y-filter S=16: 256 outs, 1/thread
            int y2 = tid >> 4, x = tid & 15;
            float sum = 0.f;
#pragma unroll
            for (int t = 0; t < 8; ++t) {          // rows 4y2-2+t -> padded 4y2+t
                float w = 1.f - fabsf((float)t - 3.5f) * 0.25f;
                sum = fmaf(w, xf16P[(4 * y2 + t) * 19 + x], sum);
            }
            float wsum = (y2 == 0 || y2 == 15) ? 3.5f : 4.0f;
            o16[bc * 16384 + z * 256 + y2 * 16 + x] = sum / wsum;  // coalesced 1 KB
        }
        if (tid < 64) {                            // y-filter S=8: 64 outs
            int y2 = tid >> 3, x = tid & 7;
            float sum = 0.f;
#pragma unroll
            for (int t = 0; t < 16; ++t) {         // rows 8y2-4+t -> padded 8y2+t
                float w = 1.f - fabsf((float)t - 7.5f) * 0.125f;
                sum = fmaf(w, xf8P[(8 * y2 + t) * 9 + x], sum);
            }
            float wsum = (y2 == 0 || y2 == 7) ? 7.f : 8.f;
            o8[bc * 4096 + z * 64 + y2 * 8 + x] = sum / wsum;      // coalesced 256 B
        }
    } else {
        // ---- transpose [b][32][N] -> [b][N][32], 64-point tiles (verified R7) ----
        float* tile = lds;                         // 64*33 = 2112 floats, fits overlay
        int tl = bx - 768;                         // 0..287
        const float* din; float* dout; int N, b, n0;
        if (tl < 256) { din = by ? td0 : sd0; dout = by ? td0T : sd0T;
                        N = N0; b = tl >> 6; n0 = (tl & 63) * 64; }
        else { tl -= 256; din = by ? td1 : sd1; dout = by ? td1T : sd1T;
               N = N1; b = tl >> 3; n0 = (tl & 7) * 64; }
#pragma unroll
        for (int i = 0; i < 8; ++i) {              // load: coalesced 64-float rows
            int idx = tid + i * 256;
            int c = idx >> 6, j = idx & 63;
            tile[j * 33 + c] = din[((size_t)b * CDESC + c) * N + n0 + j];
        }
        __syncthreads();
#pragma unroll
        for (int i = 0; i < 8; ++i) {              // store: contiguous 32-float points
            int idx = tid + i * 256;
            int p = idx >> 5, c = idx & 31;
            dout[((size_t)b * N + n0 + p) * CDESC + c] = tile[p * 33 + c];
        }
    }
}

// ======================= K2: z-filter only (both stages) =======================
// R11 (verified). R15: also initializes K3's cross-block argmin state
// (gkeys sentinels + group tickets) -- stream order guarantees visibility.
__global__ __launch_bounds__(256) void pass2z(
        const float* __restrict__ x16a, const float* __restrict__ x16b,
        const float* __restrict__ x8a,  const float* __restrict__ x8b,
        float4* __restrict__ ps0, float4* __restrict__ pt0,
        float4* __restrict__ ps1, float4* __restrict__ pt1,
        u64* __restrict__ gkeys, unsigned* __restrict__ gtick) {
    int gid = blockIdx.x * 256 + threadIdx.x;
    if (gid < 16384) gkeys[gid] = ~0ull;           // argmin sentinels (stage-0)
    else if (gid < 16448) gtick[gid - 16384] = 0u; // 64 group tickets
    if (blockIdx.x < 128) {                        // stage-0: 32768 points
        int side = gid >> 14, r = gid & 16383;
        int b = r >> 12, n = r & 4095;
        int x = n & 15, y = (n >> 4) & 15, z = n >> 8;
        const float* t = side ? x16b : x16a;
        const float* base = t + (size_t)b * 49152 + y * 16 + x;  // b*3ch*16384
        float a0 = 0.f, a1 = 0.f, a2 = 0.f, wzs = 0.f;
#pragma unroll
        for (int tt = 0; tt < 8; ++tt) {
            float w = 1.f - fabsf((float)tt - 3.5f) * 0.25f;
            int jz = 4 * z - 2 + tt;
            if ((unsigned)jz < 64u) {
                const float* p = base + jz * 256;
                a0 = fmaf(w, p[0],     a0);
                a1 = fmaf(w, p[16384], a1);
                a2 = fmaf(w, p[32768], a2);
                wzs += w;
            }
        }
        float inv = 1.f / wzs;
        a0 *= inv; a1 *= inv; a2 *= inv;
        float sq = a0 * a0 + a1 * a1 + a2 * a2;
        if (side) pt0[b * N0 + n] = make_float4(-2.f * a0, -2.f * a1, -2.f * a2, sq);
        else      ps0[b * N0 + n] = make_float4(a0, a1, a2, sq);
    } else {                                       // stage-1: 4096 points
        int g = gid - 32768;
        int side = g >> 11, r = g & 2047;
        int b = r >> 9, n = r & 511;
        int x = n & 7, y = (n >> 3) & 7, z = n >> 6;
        const float* t = side ? x8b : x8a;
        const float* base = t + (size_t)b * 12288 + y * 8 + x;   // b*3ch*4096
        float a0 = 0.f, a1 = 0.f, a2 = 0.f, wzs = 0.f;
#pragma unroll
        for (int tt = 0; tt < 16; ++tt) {
            float w = 1.f - fabsf((float)tt - 7.5f) * 0.125f;
            int jz = 8 * z - 4 + tt;
            if ((unsigned)jz < 64u) {
                const float* p = base + jz * 64;
                a0 = fmaf(w, p[0],    a0);
                a1 = fmaf(w, p[4096], a1);
                a2 = fmaf(w, p[8192], a2);
                wzs += w;
            }
        }
        float inv = 1.f / wzs;
        a0 *= inv; a1 *= inv; a2 *= inv;
        float sq = a0 * a0 + a1 * a1 + a2 * a2;
        if (side) pt1[b * N1 + n] = make_float4(-2.f * a0, -2.f * a1, -2.f * a2, sq);
        else      ps1[b * N1 + n] = make_float4(a0, a1, a2, sq);
    }
}

// cosine of two point-major 32-float descriptors (coalesced float4 reads)
__device__ __forceinline__ float cos_pm(const float* __restrict__ sT,
                                        const float* __restrict__ tT,
                                        size_t si, size_t ti) {
    const float4* s = (const float4*)(sT + si * CDESC);
    const float4* t = (const float4*)(tT + ti * CDESC);
    float num = 0.f, s2 = 0.f, t2 = 0.f;
#pragma unroll
    for (int c = 0; c < 8; ++c) {
        float4 a = s[c], g = t[c];
        num = fmaf(a.x, g.x, fmaf(a.y, g.y, fmaf(a.z, g.z, fmaf(a.w, g.w, num))));
        s2  = fmaf(a.x, a.x, fmaf(a.y, a.y, fmaf(a.z, a.z, fmaf(a.w, a.w, s2))));
        t2  = fmaf(g.x, g.x, fmaf(g.y, g.y, fmaf(g.z, g.z, fmaf(g.w, g.w, t2))));
    }
    return num / (fmaxf(sqrtf(s2), 1e-8f) * fmaxf(sqrtf(t2), 1e-8f));
}

// d2 (minus the constant |s|^2 term) from a point P and a pre-transformed candidate Q
__device__ __forceinline__ float dist_pm(float4 P, float4 Q) {
    return fmaf(P.x, Q.x, fmaf(P.y, Q.y, fmaf(P.z, Q.z, Q.w)));
}

// min of 8 via chain-free tree (7 fminf)
__device__ __forceinline__ float min8(const float* d) {
    float e0 = fminf(d[0], d[1]), e1 = fminf(d[2], d[3]);
    float e2 = fminf(d[4], d[5]), e3 = fminf(d[6], d[7]);
    return fminf(fminf(e0, e1), fminf(e2, e3));
}

// ======================= K3: argmin + cosine =======================
// R16: candidate-split (R15, DS-balanced) + batch-8 min-tree (R3's VALU trick).
// R15's per-candidate `if(d<b){..}` was 4x(cmp+2 cndmask)/candidate -> stage-0
// VALU-bound (~24 VALU/cand-iter). Batch-8: per candidate 3 fma + 1 fminf per
// point (chain-free tree), one strict-< select per batch -> ~17/iter (-29%).
// First-min exactness (verified R3 scheme): ascending batches + strict < keeps
// the FIRST batch holding the min; descending equality re-scan of that batch
// (same LDS data, same fmaf chain) yields the first index. Cross-window/block
// combine via u64 (mono(d)<<32|m) atomicMin == lexicographic == jnp.argmin.
// Block=(b, 256-pt group g, quarter q); 4 waves x 256-cand windows; 4 pts/lane.
// 4th-arriving block per group (ticket) computes the 256 cosines.
// blocks 256..263: stage-1 (R3 verified body). 264-ticket finalizer unchanged.
__global__ __launch_bounds__(256) void nn_cos_all(
        const float4* __restrict__ ps0, const float4* __restrict__ pt0,
        const float* __restrict__ sd0T, const float* __restrict__ td0T,
        const float4* __restrict__ ps1, const float4* __restrict__ pt1,
        const float* __restrict__ sd1T, const float* __restrict__ td1T,
        u64* __restrict__ gkeys, unsigned* __restrict__ gtick,
        float* acc, float* __restrict__ out) {
    extern __shared__ __align__(16) char smraw[];  // 24 KB dynamic
    float4* sm = (float4*)smraw;
    __shared__ unsigned sflag;
    const int tid = threadIdx.x;
    const int bx  = blockIdx.x;

    if (bx < 256) {
        int b = bx >> 6, g = (bx >> 2) & 15, q = bx & 3;
        const float4* tp = pt0 + b * N0 + q * 1024;
        for (int i = tid; i < 1024; i += 256)      // stage this quarter (16 KB)
            sm[i] = tp[i];                         // pre-transformed in pass2z
        int lane = tid & 63, w = tid >> 6;
        int pbase = b * N0 + g * 256 + lane;
        float4 P0 = ps0[pbase];
        float4 P1 = ps0[pbase + 64];
        float4 P2 = ps0[pbase + 128];
        float4 P3 = ps0[pbase + 192];
        __syncthreads();
        const int m0 = w * 256;                    // this wave's window in the quarter
        float b0 = FLT_MAX, b1 = FLT_MAX, b2 = FLT_MAX, b3 = FLT_MAX;
        int a0 = 0, a1 = 0, a2 = 0, a3 = 0;        // winning batch bases
        for (int k0 = 0; k0 < 256; k0 += 8) {
            float d0[8], d1[8], d2[8], d3[8];
#pragma unroll
            for (int u = 0; u < 8; ++u) {
                float4 Q = sm[m0 + k0 + u];        // broadcast, conflict-free
                d0[u] = dist_pm(P0, Q);
                d1[u] = dist_pm(P1, Q);
                d2[u] = dist_pm(P2, Q);
                d3[u] = dist_pm(P3, Q);
            }
            float m0v = min8(d0), m1v = min8(d1), m2v = min8(d2), m3v = min8(d3);
            if (m0v < b0) { b0 = m0v; a0 = k0; }   // strict <: keeps first batch
            if (m1v < b1) { b1 = m1v; a1 = k0; }
            if (m2v < b2) { b2 = m2v; a2 = k0; }
            if (m3v < b3) { b3 = m3v; a3 = k0; }
        }
        int i0 = 0, i1 = 0, i2 = 0, i3 = 0;
#pragma unroll
        for (int u = 7; u >= 0; --u) {             // descending: ends at FIRST match
            if (dist_pm(P0, sm[m0 + a0 + u]) == b0) i0 = u;
            if (dist_pm(P1, sm[m0 + a1 + u]) == b1) i1 = u;
            if (dist_pm(P2, sm[m0 + a2 + u]) == b2) i2 = u;
            if (dist_pm(P3, sm[m0 + a3 + u]) == b3) i3 = u;
        }
        int mb = q * 1024 + m0;                    // global m of window base
        u64* keys = (u64*)(smraw + 16384);         // 8 KB key region after sm
        keys[w * 256 + lane      ] = ((u64)fbits_mono(b0) << 32) | (unsigned)(mb + a0 + i0);
        keys[w * 256 + lane + 64 ] = ((u64)fbits_mono(b1) << 32) | (unsigned)(mb + a1 + i1);
        keys[w * 256 + lane + 128] = ((u64)fbits_mono(b2) << 32) | (unsigned)(mb + a2 + i2);
        keys[w * 256 + lane + 192] = ((u64)fbits_mono(b3) << 32) | (unsigned)(mb + a3 + i3);
        __syncthreads();
        {                                          // combine 4 windows, point p=tid
            u64 k0 = keys[tid],       k1 = keys[256 + tid];
            u64 k2 = keys[512 + tid], k3 = keys[768 + tid];
            u64 ka = k0 < k1 ? k0 : k1;
            u64 kb = k2 < k3 ? k2 : k3;
            u64 kk = ka < kb ? ka : kb;
            atomicMin(&gkeys[(size_t)b * N0 + g * 256 + tid], kk);
        }
        __syncthreads();                           // barrier drains all atomics (vmcnt 0)
        if (tid == 0) sflag = atomicAdd(&gtick[b * 16 + g], 1u);
        __syncthreads();
        if (sflag == 3u) {                         // last of the group's 4 quarters
            u64 kk = atomicAdd(&gkeys[(size_t)b * N0 + g * 256 + tid], 0ull);  // L2 read
            int nearest = (int)(unsigned)(kk & 0xFFFFFFFFull);
            int n2 = g * 256 + tid;
            float cosv = cos_pm(sd0T, td0T, (size_t)b * N0 + n2,
                                (size_t)b * N0 + nearest);
            wave_reduce_atomic(cosv, acc + 0);
        }
    } else {
        int bb = bx - 256;
        int b = bb >> 1;
        const float4* tp = pt1 + b * N1;
        for (int i = tid; i < N1; i += 256)
            sm[i] = tp[i];                         // pre-transformed in pass2z
        __syncthreads();
        int n = (bb & 1) * 256 + tid;
        float4 P = ps1[b * N1 + n];
        float best = FLT_MAX; int bbase = 0;
        for (int k0 = 0; k0 < N1; k0 += 16) {
            float d[16];
#pragma unroll
            for (int u = 0; u < 16; ++u)
                d[u] = dist_pm(P, sm[k0 + u]);
            float e0 = fminf(d[0],  d[1]),  e1 = fminf(d[2],  d[3]);
            float e2 = fminf(d[4],  d[5]),  e3 = fminf(d[6],  d[7]);
            float e4 = fminf(d[8],  d[9]),  e5 = fminf(d[10], d[11]);
            float e6 = fminf(d[12], d[13]), e7 = fminf(d[14], d[15]);
            float f0 = fminf(e0, e1), f1 = fminf(e2, e3);
            float f2 = fminf(e4, e5), f3 = fminf(e6, e7);
            float bm = fminf(fminf(f0, f1), fminf(f2, f3));
            if (bm < best) { best = bm; bbase = k0; }
        }
        int bi = 0;
#pragma unroll
        for (int u = 15; u >= 0; --u) {            // descending: ends at FIRST match
            float dv = dist_pm(P, sm[bbase + u]);
            if (dv == best) bi = u;
        }
        float cosv = cos_pm(sd1T, td1T, (size_t)b * N1 + n,
                            (size_t)b * N1 + bbase + bi);
        wave_reduce_atomic(cosv, acc + 1);
    }

    __syncthreads();                               // block's atomics all issued
    if (tid == 0) {
        __threadfence();
        unsigned old = atomicAdd((unsigned*)(acc + 2), 1u);
        if (old == 263u) {                         // last of 264 blocks
            float a0 = atomicAdd(acc + 0, 0.f);
            float a1 = atomicAdd(acc + 1, 0.f);
            out[0] = 1.f - 0.5f * (a0 * (1.f / 16384.f) + a1 * (1.f / 2048.f));
        }
    }
}

extern "C" void kernel_launch(void* const* d_in, const int* in_sizes, int n_in,
                              void* d_out, int out_size, void* d_ws, size_t ws_size,
                              hipStream_t stream) {
    const float* c_src = (const float*)d_in[0];   // [4,3,64,64,64]
    const float* c_tgt = (const float*)d_in[1];
    const float* sd0   = (const float*)d_in[2];   // [4,32,16,16,16]
    const float* td0   = (const float*)d_in[3];
    const float* sd1   = (const float*)d_in[4];   // [4,32,8,8,8]
    const float* td1   = (const float*)d_in[5];
    float* out = (float*)d_out;

    char* ws = (char*)d_ws;
    float* acc  = (float*)ws;                      // [0]=sum0 [1]=sum1 [2]=ticket
    float* x16a = (float*)(ws + 256);              // 196608 floats each [bc][z][16][16]
    float* x16b = x16a + 196608;
    float* x8a  = x16b + 196608;                   // 49152 floats each [bc][z][8][8]
    float* x8b  = x8a + 49152;
    float4* ps0 = (float4*)(x8b + 49152);          // 16384 float4
    float4* pt0 = ps0 + 16384;
    float4* ps1 = pt0 + 16384;                     // 2048 float4
    float4* pt1 = ps1 + 2048;
    float* sd0T = (float*)(pt1 + 2048);            // 524288 floats each
    float* td0T = sd0T + 524288;
    float* sd1T = td0T + 524288;                   // 65536 floats each
    float* td1T = sd1T + 65536;
    u64* gkeys  = (u64*)(td1T + 65536);            // 16384 u64 partial-argmin keys
    unsigned* gtick = (unsigned*)(gkeys + 16384);  // 64 group tickets

    pass1_fused<<<dim3(1056, 2), 256, 0, stream>>>(c_src, c_tgt, sd0, td0, sd1, td1,
                                                   x16a, x16b, x8a, x8b,
                                                   sd0T, td0T, sd1T, td1T, acc);
    pass2z<<<144, 256, 0, stream>>>(x16a, x16b, x8a, x8b, ps0, pt0, ps1, pt1,
                                    gkeys, gtick);
    nn_cos_all<<<264, 256, 24576, stream>>>(ps0, pt0, sd0T, td0T, ps1, pt1,
                                            sd1T, td1T, gkeys, gtick, acc, out);
}